// Round 21
// baseline (1669.117 us; speedup 1.0000x reference)
//
#include <hip/hip_runtime.h>
#include <math.h>

#define NN   10000      // nodes
#define DD   512        // node dim
#define NH   8          // node heads (DK=64)
#define NE   120000     // edges (global)
#define NEL  60000      // local edges
#define NLG  600000     // line-graph edges
#define ED   64         // edge dim (EH=8, EDK=8)
#define NEH  8
#define NL   4          // layers
#define QKVW 1536       // fused q|k|v row width

typedef __attribute__((ext_vector_type(8))) short bf16x8;
typedef __attribute__((ext_vector_type(8))) unsigned short u16x8;
typedef __attribute__((ext_vector_type(4))) float f32x4;

__device__ __forceinline__ unsigned short f2b(float f) {
    union { float f; unsigned u; } c; c.f = f;
    unsigned u = c.u;
    unsigned r = u + 0x7FFFu + ((u >> 16) & 1u);
    return (unsigned short)(r >> 16);
}
__device__ __forceinline__ float b2f(unsigned short b) {
    union { unsigned u; float f; } c; c.u = ((unsigned)b) << 16;
    return c.f;
}

// async global->LDS, 16B per lane; LDS dest is wave-uniform base + lane*16 (HW)
__device__ __forceinline__ void gl16(const unsigned short* g, unsigned short* l) {
    __builtin_amdgcn_global_load_lds(
        (const __attribute__((address_space(1))) unsigned int*)g,
        (__attribute__((address_space(3))) unsigned int*)l, 16, 0, 0);
}

// ---------------- fused init: castcopy + lgb init + el gather --------------
static __global__ __launch_bounds__(256)
void init_all_k(const float* __restrict__ x_in, const float* __restrict__ rel,
                const int* __restrict__ ef, const int* __restrict__ lidx,
                float* __restrict__ xbuf, unsigned short* __restrict__ xb,
                unsigned short* __restrict__ lgb,
                float* __restrict__ el, unsigned short* __restrict__ elb)
{
    long i = (long)blockIdx.x * 256 + threadIdx.x;
    const long n1 = (long)NN * DD, n2 = n1 + (long)NE * ED, n3 = n2 + (long)NEL * ED;
    if (i < n1) {
        float v = x_in[i]; xbuf[i] = v; xb[i] = f2b(v);
    } else if (i < n2) {
        long k = i - n1; int e = (int)(k >> 6), c = (int)(k & 63);
        lgb[k] = f2b(rel[(long)ef[e] * ED + c]);
    } else if (i < n3) {
        long k = i - n2; int r = (int)(k >> 6), c = (int)(k & 63);
        unsigned short b = f2b(rel[(long)ef[lidx[r]] * ED + c]);
        el[k] = b2f(b); elb[k] = b;
    }
}

// ---------------- fused weight transpose+cast (all 15 segments) ------------
#define NSEG 15
struct TT {
    const float* src[NSEG];
    unsigned short* dst[NSEG];
    long lstride[NSEG];
    int K[NSEG], Nn[NSEG], rowStride[NSEG], rowOff[NSEG], colOff[NSEG];
    int blkStart[NSEG];
};

static __global__ __launch_bounds__(256)
void ttrans_all_k(TT t) {
    const int bid = blockIdx.x;
    int s = 0;
    #pragma unroll
    for (int i = 1; i < NSEG; ++i) s += (bid >= t.blkStart[i]);
    const int local = bid - t.blkStart[s];
    const int K = t.K[s], N = t.Nn[s];
    const int nKb = K >> 5;
    const int perL = nKb * (N >> 5);
    const int l = local / perL;
    const int rem = local - l * perL;
    const int kt = (rem % nKb) * 32;
    const int nt = (rem / nKb) * 32;
    __shared__ float sm[32][33];
    const int tx = threadIdx.x & 31, ty = threadIdx.x >> 5;
    const float* ip = t.src[s] + (size_t)l * K * N;
    #pragma unroll
    for (int r = 0; r < 4; ++r)
        sm[ty + 8 * r][tx] = ip[(size_t)(kt + ty + 8 * r) * N + nt + tx];
    __syncthreads();
    unsigned short* op = t.dst[s] + (size_t)l * t.lstride[s];
    #pragma unroll
    for (int r = 0; r < 4; ++r) {
        int n = nt + ty + 8 * r;
        op[(size_t)(t.rowOff[s] + n) * t.rowStride[s] + t.colOff[s] + kt + tx] =
            f2b(sm[tx][ty + 8 * r]);
    }
}

// ---------------- fused bias prep ----------------
static __global__ __launch_bounds__(256)
void biases_k(const float* __restrict__ bq, const float* __restrict__ ndb,
              const float* __restrict__ eqb, const float* __restrict__ nsb,
              float* __restrict__ qkvb, float* __restrict__ kvb,
              float* __restrict__ qb2)
{
    int i = blockIdx.x * 256 + threadIdx.x;
    if (i < NL * QKVW) { int l = i / QKVW, c = i - l * QKVW; qkvb[i] = (c < 512) ? bq[l * 512 + c] : 0.0f; }
    if (i < NL * 128) kvb[i] = ndb[(i >> 7) * 64 + (i & 63)];
    if (i < NL * 64)  qb2[i] = eqb[i] + nsb[i];
}

// ---------------- CSR build (both graphs fused per stage) ------------------
static __global__ __launch_bounds__(256)
void zero2_k(int* __restrict__ gcnt, int* __restrict__ ecnt) {
    int i = blockIdx.x * 256 + threadIdx.x;
    if (i < NN)  gcnt[i] = 0;
    if (i < NEL) ecnt[i] = 0;
}

static __global__ __launch_bounds__(256)
void hist2_k(const int* __restrict__ gdst, const int* __restrict__ ldst,
             int* __restrict__ gcnt, int* __restrict__ ecnt) {
    int i = blockIdx.x * 256 + threadIdx.x;
    if (i < NE) atomicAdd(&gcnt[gdst[i]], 1);
    else if (i < NE + NLG) atomicAdd(&ecnt[ldst[i - NE]], 1);
}

static __global__ __launch_bounds__(256)
void scanA2_k(const int* __restrict__ gcnt, const int* __restrict__ ecnt,
              int* __restrict__ goff, int* __restrict__ eoff,
              int* __restrict__ bsum, int nbG) {
    __shared__ int sm[256];
    const int t = threadIdx.x;
    const bool isG = blockIdx.x < (unsigned)nbG;
    const int b = isG ? blockIdx.x : blockIdx.x - nbG;
    const int n = isG ? NN : NEL;
    const int* cnt = isG ? gcnt : ecnt;
    int* off = isG ? goff : eoff;
    int* bs = bsum + (isG ? 0 : 512);
    const int i = b * 256 + t;
    int v = (i < n) ? cnt[i] : 0;
    sm[t] = v; __syncthreads();
    int x = v;
    #pragma unroll
    for (int d = 1; d < 256; d <<= 1) {
        int y = (t >= d) ? sm[t - d] : 0;
        __syncthreads();
        x += y; sm[t] = x; __syncthreads();
    }
    if (i < n) off[i] = x - v;
    if (t == 255) bs[b] = x;
}

static __global__ __launch_bounds__(1024)
void scanB2_k(int* __restrict__ bsum, int nbG, int nbE) {
    __shared__ int sm[1024];
    const int t = threadIdx.x;
    int* bs = bsum + (blockIdx.x ? 512 : 0);
    const int nb = blockIdx.x ? nbE : nbG;
    int v = (t < nb) ? bs[t] : 0;
    sm[t] = v; __syncthreads();
    int x = v;
    #pragma unroll
    for (int d = 1; d < 1024; d <<= 1) {
        int y = (t >= d) ? sm[t - d] : 0;
        __syncthreads();
        x += y; sm[t] = x; __syncthreads();
    }
    if (t < nb) bs[t] = x - v;
}

static __global__ __launch_bounds__(256)
void scanC2_k(const int* __restrict__ bsum, int* __restrict__ goff,
              int* __restrict__ eoff, int* __restrict__ gcur,
              int* __restrict__ ecur, int nbG) {
    const bool isG = blockIdx.x < (unsigned)nbG;
    const int b = isG ? blockIdx.x : blockIdx.x - nbG;
    const int n = isG ? NN : NEL;
    int* off = isG ? goff : eoff;
    int* cur = isG ? gcur : ecur;
    const int* bs = bsum + (isG ? 0 : 512);
    int i = b * 256 + threadIdx.x;
    if (i < n) { int o = off[i] + bs[b]; off[i] = o; cur[i] = o; }
}

static __global__ __launch_bounds__(256)
void scatterpack_k(const int* __restrict__ gdst, const int* __restrict__ ldst,
                   const int* __restrict__ gsrc, const int* __restrict__ lsrc,
                   int* __restrict__ gcur, int* __restrict__ ecur,
                   int2* __restrict__ npack, int* __restrict__ esrc) {
    int i = blockIdx.x * 256 + threadIdx.x;
    if (i < NE) {
        int p = atomicAdd(&gcur[gdst[i]], 1);
        npack[p] = make_int2(i, gsrc[i]);
    } else if (i < NE + NLG) {
        int k = i - NE;
        int p = atomicAdd(&ecur[ldst[k]], 1);
        esrc[p] = lsrc[k];
    }
}

// ---------------- segmented bf16 MFMA GEMM (up to 3 independent GEMMs) -----
// Proven 64x64/BK=64/single-buffered body; block table selects segment.
// Segment outputs MUST be disjoint (concurrent execution).
struct GSeg {
    const unsigned short* A;
    const unsigned short* A2;     // null => plain A[M,K]
    const int* idx2;
    const unsigned short* Bt;
    const float* bias;
    const unsigned short* addCb;  // may be null
    unsigned short* Cb;
    int M, K, Nc, K1, blkStart, gridX, doRelu;
};
struct GSegs { GSeg s[3]; int nseg; int total; };

static __global__ __launch_bounds__(256)
void gemmseg_k(GSegs g)
{
    __shared__ unsigned short Asl[64 * 64];
    __shared__ unsigned short Bsl[64 * 64];
    const int tid  = threadIdx.x;
    const int lane = tid & 63;
    const int wave = tid >> 6;
    const int wr = (wave >> 1) * 32;
    const int wc = (wave & 1) * 32;

    // XCD-aware bijective block swizzle (m204) over the combined grid
    const int nwg = g.total;
    const int hw = blockIdx.x;
    const int q8 = nwg >> 3, r8 = nwg & 7;
    const int xcd = hw & 7, rest = hw >> 3;
    const int logical = (xcd < r8 ? xcd * (q8 + 1) : r8 * (q8 + 1) + (xcd - r8) * q8) + rest;

    int si = 0;
    #pragma unroll
    for (int i = 1; i < 3; ++i) si += (i < g.nseg && logical >= g.s[i].blkStart);
    const GSeg S = g.s[si];
    const int local = logical - S.blkStart;
    const int bm = (local / S.gridX) * 64;
    const int bn = (local % S.gridX) * 64;
    const int M = S.M, K = S.K, Nc = S.Nc, K1 = S.K1;

    const int rl8 = lane >> 3;
    const int sl8 = lane & 7;
    int ga[2]; long ia[2]; bool av[2]; int acw[2];
    int gb[2]; int bcw[2];
    #pragma unroll
    for (int c = 0; c < 2; ++c) {
        int ar = wave * 16 + c * 8 + rl8;
        ga[c] = bm + ar;
        av[c] = ga[c] < M;
        ia[c] = (S.A2 && av[c]) ? (long)S.idx2[ga[c]] : 0;
        acw[c] = (sl8 ^ (ar & 7)) * 8;
        int br = wave * 16 + c * 8 + rl8;
        gb[c] = bn + br;
        bcw[c] = (sl8 ^ (br & 7)) * 8;
    }

    auto stage = [&](int k0) {
        #pragma unroll
        for (int c = 0; c < 2; ++c) {
            const unsigned short* s;
            if (!S.A2)          s = S.A  + (long)ga[c] * K  + k0 + acw[c];
            else if (k0 < K1)   s = S.A  + (long)ga[c] * K1 + k0 + acw[c];
            else                s = S.A2 + ia[c] * DD + (k0 - K1) + acw[c];
            if (av[c]) gl16(s, Asl + (wave * 16 + c * 8) * 64);
            gl16(S.Bt + (long)gb[c] * K + k0 + bcw[c], Bsl + (wave * 16 + c * 8) * 64);
        }
    };

    f32x4 acc[2][2] = {};
    const int rbase = lane & 15;
    const int ks = lane >> 4;

    for (int k0 = 0; k0 < K; k0 += 64) {
        stage(k0);
        __syncthreads();
        #pragma unroll
        for (int h = 0; h < 2; ++h) {
            bf16x8 af[2], bfr[2];
            #pragma unroll
            for (int mi = 0; mi < 2; ++mi) {
                int r = wr + mi * 16 + rbase;
                int p = (h * 4 + ks) ^ (r & 7);
                af[mi] = *reinterpret_cast<const bf16x8*>(Asl + r * 64 + p * 8);
            }
            #pragma unroll
            for (int ni = 0; ni < 2; ++ni) {
                int r = wc + ni * 16 + rbase;
                int p = (h * 4 + ks) ^ (r & 7);
                bfr[ni] = *reinterpret_cast<const bf16x8*>(Bsl + r * 64 + p * 8);
            }
            #pragma unroll
            for (int mi = 0; mi < 2; ++mi)
                #pragma unroll
                for (int ni = 0; ni < 2; ++ni)
                    acc[mi][ni] = __builtin_amdgcn_mfma_f32_16x16x32_bf16(
                        af[mi], bfr[ni], acc[mi][ni], 0, 0, 0);
        }
        __syncthreads();
    }

    const int colBase = bn + wc + rbase;
    const int rowBase = bm + wr + ks * 4;
    #pragma unroll
    for (int mi = 0; mi < 2; ++mi) {
        #pragma unroll
        for (int j = 0; j < 4; ++j) {
            int r = rowBase + mi * 16 + j;
            if (r >= M) continue;
            long ro = (long)r * Nc;
            #pragma unroll
            for (int ni = 0; ni < 2; ++ni) {
                int cc = colBase + ni * 16;
                if (cc >= Nc) continue;
                float v = acc[mi][ni][j];
                if (S.bias)  v += S.bias[cc];
                if (S.doRelu) v = fmaxf(v, 0.0f);
                if (S.addCb) v += b2f(S.addCb[ro + cc]);
                S.Cb[ro + cc] = f2b(v);
            }
        }
    }
}

// ---------------- segmented LayerNorm (2 independent LNs) ----------------
struct LNSeg {
    const unsigned short* inb;
    const float* g; const float* b;
    float* out;                 // may be null
    unsigned short* outb;       // may be null
    unsigned short* out2b;      // may be null (scatter via idx2)
    const int* idx2;
    int Dw, nrows, blkStart;
};
struct LNSegs { LNSeg s[2]; };

static __global__ __launch_bounds__(256)
void ln2_k(LNSegs L)
{
    const int sidx = (blockIdx.x >= (unsigned)L.s[1].blkStart) ? 1 : 0;
    const LNSeg S = L.s[sidx];
    const int row = (blockIdx.x - S.blkStart) * 4 + (threadIdx.x >> 6);
    if (row >= S.nrows) return;
    const int lane = threadIdx.x & 63;
    const int per = S.Dw >> 6;
    float v[8];
    float s = 0.f;
    const unsigned short* rp = S.inb + (long)row * S.Dw;
    for (int i = 0; i < per; ++i) { v[i] = b2f(rp[i * 64 + lane]); s += v[i]; }
    #pragma unroll
    for (int off = 32; off; off >>= 1) s += __shfl_xor(s, off, 64);
    const float mu = s / (float)S.Dw;
    float var = 0.f;
    for (int i = 0; i < per; ++i) { float d = v[i] - mu; var += d * d; }
    #pragma unroll
    for (int off = 32; off; off >>= 1) var += __shfl_xor(var, off, 64);
    const float rstd = rsqrtf(var / (float)S.Dw + 1e-5f);
    for (int i = 0; i < per; ++i) {
        int c = i * 64 + lane;
        float o = (v[i] - mu) * rstd * S.g[c] + S.b[c];
        if (S.out)   S.out[(long)row * S.Dw + c] = o;
        if (S.outb)  S.outb[(long)row * S.Dw + c] = f2b(o);
        if (S.out2b) S.out2b[(long)S.idx2[row] * S.Dw + c] = f2b(o);
    }
}

// ---------------- merged attention (node [0,NN/4) | lg [NN/4,..)) ----------
__device__ __forceinline__ void node_attn_body(
    const unsigned short* __restrict__ qkv, const unsigned short* __restrict__ lgb,
    const int* __restrict__ goff, const int2* __restrict__ npack,
    unsigned short* __restrict__ ob, int node, int lane)
{
    float qv[8];
    {
        u16x8 q8 = *reinterpret_cast<const u16x8*>(qkv + (long)node * QKVW + lane * 8);
        #pragma unroll
        for (int i = 0; i < 8; ++i) qv[i] = b2f(q8[i]);
    }
    float wva[8] = {0.f, 0.f, 0.f, 0.f, 0.f, 0.f, 0.f, 0.f};
    float zac = 0.f;
    int j = goff[node];
    const int hi = (node + 1 < NN) ? goff[node + 1] : NE;
    const int eoffl = (lane & 7) * 8;

    for (; j + 2 <= hi; j += 2) {
        int2 pa = npack[j], pb = npack[j + 1];
        u16x8 kA = *reinterpret_cast<const u16x8*>(qkv + (long)pa.y * QKVW + 512 + lane * 8);
        u16x8 vA = *reinterpret_cast<const u16x8*>(qkv + (long)pa.y * QKVW + 1024 + lane * 8);
        u16x8 eA = *reinterpret_cast<const u16x8*>(lgb + (long)pa.x * ED + eoffl);
        u16x8 kB = *reinterpret_cast<const u16x8*>(qkv + (long)pb.y * QKVW + 512 + lane * 8);
        u16x8 vB = *reinterpret_cast<const u16x8*>(qkv + (long)pb.y * QKVW + 1024 + lane * 8);
        u16x8 eB = *reinterpret_cast<const u16x8*>(lgb + (long)pb.x * ED + eoffl);
        float edA[8], vvA[8], edB[8], vvB[8];
        float pA = 0.f, pB = 0.f;
        #pragma unroll
        for (int i = 0; i < 8; ++i) {
            edA[i] = b2f(eA[i]); vvA[i] = b2f(vA[i]);
            pA = fmaf(b2f(kA[i]) + edA[i], qv[i], pA);
            edB[i] = b2f(eB[i]); vvB[i] = b2f(vB[i]);
            pB = fmaf(b2f(kB[i]) + edB[i], qv[i], pB);
        }
        pA += __shfl_xor(pA, 1, 64); pA += __shfl_xor(pA, 2, 64); pA += __shfl_xor(pA, 4, 64);
        pB += __shfl_xor(pB, 1, 64); pB += __shfl_xor(pB, 2, 64); pB += __shfl_xor(pB, 4, 64);
        float wA = expf(fminf(fmaxf(pA * 0.125f, -10.0f), 10.0f));
        float wB = expf(fminf(fmaxf(pB * 0.125f, -10.0f), 10.0f));
        #pragma unroll
        for (int i = 0; i < 8; ++i) {
            wva[i] = fmaf(wA, vvA[i] + edA[i], wva[i]);
            wva[i] = fmaf(wB, vvB[i] + edB[i], wva[i]);
        }
        zac += wA + wB;
    }
    for (; j < hi; ++j) {
        int2 pa = npack[j];
        u16x8 kA = *reinterpret_cast<const u16x8*>(qkv + (long)pa.y * QKVW + 512 + lane * 8);
        u16x8 vA = *reinterpret_cast<const u16x8*>(qkv + (long)pa.y * QKVW + 1024 + lane * 8);
        u16x8 eA = *reinterpret_cast<const u16x8*>(lgb + (long)pa.x * ED + eoffl);
        float edA[8], vvA[8];
        float pA = 0.f;
        #pragma unroll
        for (int i = 0; i < 8; ++i) {
            edA[i] = b2f(eA[i]); vvA[i] = b2f(vA[i]);
            pA = fmaf(b2f(kA[i]) + edA[i], qv[i], pA);
        }
        pA += __shfl_xor(pA, 1, 64); pA += __shfl_xor(pA, 2, 64); pA += __shfl_xor(pA, 4, 64);
        float wA = expf(fminf(fmaxf(pA * 0.125f, -10.0f), 10.0f));
        #pragma unroll
        for (int i = 0; i < 8; ++i) wva[i] = fmaf(wA, vvA[i] + edA[i], wva[i]);
        zac += wA;
    }
    const float inv = 1.0f / fmaxf(zac, 1e-9f);
    u16x8 o8;
    #pragma unroll
    for (int i = 0; i < 8; ++i) o8[i] = f2b(wva[i] * inv);
    *reinterpret_cast<u16x8*>(ob + (long)node * DD + lane * 8) = o8;
}

__device__ __forceinline__ void lg_attn_body(
    const unsigned short* __restrict__ qeb, const unsigned short* __restrict__ keve,
    const int* __restrict__ eoff, const int* __restrict__ esrc,
    unsigned short* __restrict__ oeb, int d, int lane)
{
    const int he = lane & 7;
    const int ee = lane >> 3;
    const int hd = lane >> 3;
    float qv8[8];
    {
        u16x8 q8 = *reinterpret_cast<const u16x8*>(qeb + (long)d * ED + he * 8);
        #pragma unroll
        for (int i = 0; i < 8; ++i) qv8[i] = b2f(q8[i]);
    }
    const float qvd = b2f(qeb[(long)d * ED + lane]);
    float oa = 0.f, zac = 0.f;
    int j = eoff[d];
    const int hi = (d + 1 < NEL) ? eoff[d + 1] : NLG;

    for (; j + 8 <= hi; j += 8) {
        int sMine = esrc[j + ee];
        u16x8 k8 = *reinterpret_cast<const u16x8*>(keve + (long)sMine * 128 + he * 8);
        float p = 0.f;
        #pragma unroll
        for (int i = 0; i < 8; ++i) p = fmaf(b2f(k8[i]), qv8[i], p);
        float w = expf(fminf(fmaxf(p * 0.35355339059327373f, -10.0f), 10.0f));
        #pragma unroll
        for (int u = 0; u < 8; ++u) {
            float wu = __shfl(w, u * 8 + hd, 64);
            int   su = esrc[j + u];
            float vv = b2f(keve[(long)su * 128 + 64 + lane]);
            oa = fmaf(wu, vv, oa);
            zac += wu;
        }
    }
    for (; j < hi; ++j) {
        int s = esrc[j];
        float kv = b2f(keve[(long)s * 128 + lane]);
        float vv = b2f(keve[(long)s * 128 + 64 + lane]);
        float p = kv * qvd;
        p += __shfl_xor(p, 1, 64); p += __shfl_xor(p, 2, 64); p += __shfl_xor(p, 4, 64);
        float w = expf(fminf(fmaxf(p * 0.35355339059327373f, -10.0f), 10.0f));
        oa = fmaf(w, vv, oa);
        zac += w;
    }
    oeb[(long)d * ED + lane] = f2b(oa / fmaxf(zac, 1e-9f));
}

static __global__ __launch_bounds__(256)
void attn_both_k(const unsigned short* __restrict__ qkv,
                 const unsigned short* __restrict__ lgb,
                 const int* __restrict__ goff, const int2* __restrict__ npack,
                 unsigned short* __restrict__ ob,
                 const unsigned short* __restrict__ qeb,
                 const unsigned short* __restrict__ keve,
                 const int* __restrict__ eoff, const int* __restrict__ esrc,
                 unsigned short* __restrict__ oeb)
{
    const int lane = threadIdx.x & 63;
    const int wv = threadIdx.x >> 6;
    if (blockIdx.x < NN / 4) {
        int node = blockIdx.x * 4 + wv;
        node_attn_body(qkv, lgb, goff, npack, ob, node, lane);
    } else {
        int d = (blockIdx.x - NN / 4) * 4 + wv;
        if (d < NEL) lg_attn_body(qeb, keve, eoff, esrc, oeb, d, lane);
    }
}

// ---------------- host ----------------
extern "C" void kernel_launch(void* const* d_in, const int* in_sizes, int n_in,
                              void* d_out, int out_size, void* d_ws, size_t ws_size,
                              hipStream_t stream)
{
    const float* x_in  = (const float*)d_in[0];
    const float* rel   = (const float*)d_in[1];
    const float* Wq    = (const float*)d_in[2];
    const float* bq    = (const float*)d_in[3];
    const float* Wk    = (const float*)d_in[4];
    const float* Wv    = (const float*)d_in[5];
    const float* Wo    = (const float*)d_in[6];
    const float* bo    = (const float*)d_in[7];
    const float* ln1g  = (const float*)d_in[8];
    const float* ln1b  = (const float*)d_in[9];
    const float* F1    = (const float*)d_in[10];
    const float* f1b   = (const float*)d_in[11];
    const float* F2    = (const float*)d_in[12];
    const float* f2b_  = (const float*)d_in[13];
    const float* ln2g  = (const float*)d_in[14];
    const float* ln2b  = (const float*)d_in[15];
    const float* Eq    = (const float*)d_in[16];
    const float* eqb   = (const float*)d_in[17];
    const float* Ek    = (const float*)d_in[18];
    const float* Ev    = (const float*)d_in[19];
    const float* Eo    = (const float*)d_in[20];
    const float* eob   = (const float*)d_in[21];
    const float* Ns    = (const float*)d_in[22];
    const float* nsb   = (const float*)d_in[23];
    const float* Nd    = (const float*)d_in[24];
    const float* ndb   = (const float*)d_in[25];
    const float* eln1g = (const float*)d_in[26];
    const float* eln1b = (const float*)d_in[27];
    const float* G1    = (const float*)d_in[28];
    const float* g1b   = (const float*)d_in[29];
    const float* G2    = (const float*)d_in[30];
    const float* g2b   = (const float*)d_in[31];
    const float* eln2g = (const float*)d_in[32];
    const float* eln2b = (const float*)d_in[33];
    const int* edge_feat   = (const int*)d_in[34];
    const int* local_index = (const int*)d_in[35];
    const int* src_ids     = (const int*)d_in[36];
    const int* dst_ids     = (const int*)d_in[37];
    const int* g_src       = (const int*)d_in[38];
    const int* g_dst       = (const int*)d_in[39];
    const int* lg_src      = (const int*)d_in[40];
    const int* lg_dst      = (const int*)d_in[41];

    // outputs live in d_out
    float* xbuf = (float*)d_out;                   // (NN, DD)
    float* el   = xbuf + (size_t)NN * DD;          // (NEL, ED)

    // ---- workspace layout ----
    float* W = (float*)d_ws;
    size_t off = 0;
    auto alloc = [&](size_t n) { float* p = W + off; off += (n + 63) & ~(size_t)63; return p; };
    float* qkvb = alloc((size_t)NL * QKVW);
    float* kvb  = alloc((size_t)NL * 128);
    float* qb2  = alloc((size_t)NL * ED);

    unsigned short* bp = (unsigned short*)(W + off);
    size_t boff = 0;
    auto balloc = [&](size_t n) { unsigned short* p = bp + boff; boff += (n + 63) & ~(size_t)63; return p; };
    unsigned short* lgb = balloc((size_t)NE * ED);
    unsigned short* xb  = balloc((size_t)NN * DD);
    unsigned short* qkv = balloc((size_t)NN * QKVW);
    // keve, qeb, t0b contiguous: gfe (edge-FFN intermediate, 15.36M) aliases
    // this region (all three dead when gfe is live: keve/qeb die after attn,
    // t0b after mid-LN; gfe written after mid-LN, consumed by G2|F2 gemmseg).
    unsigned short* keve = balloc((size_t)NEL * 128);
    unsigned short* qeb  = balloc((size_t)NEL * ED);
    unsigned short* t0b  = balloc((size_t)NN * DD);
    unsigned short* gfe  = keve;                      // NEL*4*ED = 15.36M alias
    unsigned short* elb = balloc((size_t)NEL * ED);
    unsigned short* e1b = balloc((size_t)NEL * ED);
    unsigned short* heb = balloc((size_t)NEL * ED);
    unsigned short* fgb = balloc((size_t)NN * 4 * DD);
    unsigned short* t2b = balloc((size_t)NEL * ED);   // pre-LN he
    unsigned short* t3b = balloc((size_t)NEL * ED);   // pre-LN edge out
    unsigned short* xpb = balloc((size_t)NN * DD);    // pre-LN x
    unsigned short* hb   = qkv;                       // safe: dead before next QKV write
    unsigned short* ob   = fgb;                       // safe: consumed before G1/F1 write
    unsigned short* WqkvT = balloc((size_t)NL * QKVW * DD);
    unsigned short* WoT  = balloc((size_t)NL * DD * DD);
    unsigned short* F1T  = balloc((size_t)NL * DD * 4 * DD);
    unsigned short* F2T  = balloc((size_t)NL * 4 * DD * DD);
    unsigned short* KVET = balloc((size_t)NL * 128 * 576);
    unsigned short* QET  = balloc((size_t)NL * 64 * 576);
    unsigned short* EoT  = balloc((size_t)NL * ED * ED);
    unsigned short* G1T  = balloc((size_t)NL * ED * 4 * ED);
    unsigned short* G2T  = balloc((size_t)NL * 4 * ED * ED);
    int* ip = (int*)(bp + ((boff + 63) & ~(size_t)63));
    size_t ioff = 0;
    auto ialloc = [&](size_t n) { int* p = ip + ioff; ioff += (n + 63) & ~(size_t)63; return p; };
    int* gcnt = ialloc(NN);
    int* goff = ialloc(NN);
    int* gcur = ialloc(NN);
    int2* npack = (int2*)ialloc(2 * (size_t)NE);
    int* ecnt = ialloc(NEL);
    int* eoff = ialloc(NEL);
    int* ecur = ialloc(NEL);
    int* esrc = ialloc(NLG);
    int* bsum = ialloc(1024);

    // ---- fused weight prep ----
    TT tt;
    int bc = 0, si = 0;
    auto seg = [&](const float* src, unsigned short* dst, int K, int N,
                   long lstride, int rowStride, int rowOff, int colOff) {
        tt.src[si] = src; tt.dst[si] = dst; tt.lstride[si] = lstride;
        tt.K[si] = K; tt.Nn[si] = N; tt.rowStride[si] = rowStride;
        tt.rowOff[si] = rowOff; tt.colOff[si] = colOff;
        tt.blkStart[si] = bc;
        bc += (K / 32) * (N / 32) * NL;
        ++si;
    };
    seg(Wq, WqkvT, 512, 512, (long)QKVW * DD, DD, 0, 0);
    seg(Wk, WqkvT, 512, 512, (long)QKVW * DD, DD, 512, 0);
    seg(Wv, WqkvT, 512, 512, (long)QKVW * DD, DD, 1024, 0);
    seg(Wo, WoT, 512, 512, (long)DD * DD, DD, 0, 0);
    seg(F1, F1T, 512, 2048, (long)DD * 4 * DD, DD, 0, 0);
    seg(F2, F2T, 2048, 512, (long)4 * DD * DD, 4 * DD, 0, 0);
    seg(Ek, KVET, 64, 64, (long)128 * 576, 576, 0, 0);
    seg(Nd, KVET, 512, 64, (long)128 * 576, 576, 0, 64);
    seg(Ev, KVET, 64, 64, (long)128 * 576, 576, 64, 0);
    seg(Nd, KVET, 512, 64, (long)128 * 576, 576, 64, 64);
    seg(Eq, QET, 64, 64, (long)64 * 576, 576, 0, 0);
    seg(Ns, QET, 512, 64, (long)64 * 576, 576, 0, 64);
    seg(Eo, EoT, 64, 64, (long)ED * ED, ED, 0, 0);
    seg(G1, G1T, 64, 256, (long)ED * 4 * ED, ED, 0, 0);
    seg(G2, G2T, 256, 64, (long)4 * ED * ED, 4 * ED, 0, 0);
    ttrans_all_k<<<bc, 256, 0, stream>>>(tt);
    biases_k<<<(NL * QKVW + 255) / 256, 256, 0, stream>>>(bq, ndb, eqb, nsb, qkvb, kvb, qb2);

    // ---- CSR build ----
    const int nbG = (NN + 255) / 256, nbE = (NEL + 255) / 256;
    zero2_k<<<nbE, 256, 0, stream>>>(gcnt, ecnt);
    hist2_k<<<(NE + NLG + 255) / 256, 256, 0, stream>>>(g_dst, lg_dst, gcnt, ecnt);
    scanA2_k<<<nbG + nbE, 256, 0, stream>>>(gcnt, ecnt, goff, eoff, bsum, nbG);
    scanB2_k<<<2, 1024, 0, stream>>>(bsum, nbG, nbE);
    scanC2_k<<<nbG + nbE, 256, 0, stream>>>(bsum, goff, eoff, gcur, ecur, nbG);
    scatterpack_k<<<(NE + NLG + 255) / 256, 256, 0, stream>>>(
        g_dst, lg_dst, g_src, lg_src, gcur, ecur, npack, esrc);

    // ---- fused init ----
    {
        long tot = (long)NN * DD + (long)NE * ED + (long)NEL * ED;
        init_all_k<<<(int)((tot + 255) / 256), 256, 0, stream>>>(
            x_in, rel, edge_feat, local_index, xbuf, xb, lgb, el, elb);
    }

    const int rQ = (NN + 63) / 64;    // 157
    const int rE = (NEL + 63) / 64;   // 938

    for (int i = 0; i < NL; ++i) {
        size_t oD2 = (size_t)i * DD * DD, oE2 = (size_t)i * ED * ED;

        // ---- merged {QKV | KVE | QE} ----
        {
            GSegs G;
            G.s[0] = { xb, nullptr, nullptr, WqkvT + (size_t)i * QKVW * DD,
                       qkvb + (size_t)i * QKVW, nullptr, qkv,
                       NN, DD, QKVW, 0, 0, QKVW / 64, 0 };
            int b0 = (QKVW / 64) * rQ;
            G.s[1] = { elb, xb, dst_ids, KVET + (size_t)i * 128 * 576,
                       kvb + (size_t)i * 128, nullptr, keve,
                       NEL, 576, 128, 64, b0, 2, 0 };
            int b1 = b0 + 2 * rE;
            G.s[2] = { elb, xb, src_ids, QET + (size_t)i * 64 * 576,
                       qb2 + (size_t)i * 64, nullptr, qeb,
                       NEL, 576, 64, 64, b1, 1, 0 };
            G.nseg = 3; G.total = b1 + rE;
            gemmseg_k<<<G.total, 256, 0, stream>>>(G);
        }

        // ---- merged attentions ----
        attn_both_k<<<NN / 4 + (NEL + 3) / 4, 256, 0, stream>>>(
            qkv, lgb, goff, npack, ob, qeb, keve, eoff, esrc, e1b);

        // ---- merged {Wo | Eo} ----
        {
            GSegs G;
            G.s[0] = { ob, nullptr, nullptr, WoT + oD2,
                       bo + (size_t)i * DD, xb, t0b,
                       NN, DD, DD, 0, 0, DD / 64, 0 };
            int b0 = (DD / 64) * rQ;
            G.s[1] = { e1b, nullptr, nullptr, EoT + oE2,
                       eob + (size_t)i * ED, elb, t2b,
                       NEL, ED, ED, 0, b0, 1, 0 };
            G.s[2] = G.s[1];
            G.nseg = 2; G.total = b0 + rE;
            gemmseg_k<<<G.total, 256, 0, stream>>>(G);
        }

        // ---- merged mid LNs {h | he} ----
        {
            LNSegs L;
            L.s[0] = { t0b, ln1g + (size_t)i * DD, ln1b + (size_t)i * DD,
                       nullptr, hb, nullptr, nullptr, DD, NN, 0 };
            L.s[1] = { t2b, eln1g + (size_t)i * ED, eln1b + (size_t)i * ED,
                       nullptr, heb, nullptr, nullptr, ED, NEL, (NN + 3) / 4 };
            ln2_k<<<(NN + 3) / 4 + (NEL + 3) / 4, 256, 0, stream>>>(L);
        }

        // ---- merged {G1 | F1} (relu) ----
        {
            GSegs G;
            G.s[0] = { heb, nullptr, nullptr, G1T + (size_t)i * ED * 4 * ED,
                       g1b + (size_t)i * 4 * ED, nullptr, gfe,
                       NEL, ED, 4 * ED, 0, 0, (4 * ED) / 64, 1 };
            int b0 = ((4 * ED) / 64) * rE;
            G.s[1] = { hb, nullptr, nullptr, F1T + (size_t)i * DD * 4 * DD,
                       f1b + (size_t)i * 4 * DD, nullptr, fgb,
                       NN, DD, 4 * DD, 0, b0, (4 * DD) / 64, 1 };
            G.s[2] = G.s[1];
            G.nseg = 2; G.total = b0 + ((4 * DD) / 64) * rQ;
            gemmseg_k<<<G.total, 256, 0, stream>>>(G);
        }

        // ---- merged {G2 | F2} ----
        {
            GSegs G;
            G.s[0] = { gfe, nullptr, nullptr, G2T + (size_t)i * 4 * ED * ED,
                       g2b + (size_t)i * ED, heb, t3b,
                       NEL, 4 * ED, ED, 0, 0, 1, 0 };
            int b0 = rE;
            G.s[1] = { fgb, nullptr, nullptr, F2T + (size_t)i * 4 * DD * DD,
                       f2b_ + (size_t)i * DD, hb, xpb,
                       NN, 4 * DD, DD, 0, b0, DD / 64, 0 };
            G.s[2] = G.s[1];
            G.nseg = 2; G.total = b0 + (DD / 64) * rQ;
            gemmseg_k<<<G.total, 256, 0, stream>>>(G);
        }

        // ---- merged final LNs {edge out | node out} ----
        {
            LNSegs L;
            L.s[0] = { t3b, eln2g + (size_t)i * ED, eln2b + (size_t)i * ED,
                       el, elb, lgb, local_index, ED, NEL, 0 };
            L.s[1] = { xpb, ln2g + (size_t)i * DD, ln2b + (size_t)i * DD,
                       xbuf, xb, nullptr, nullptr, DD, NN, (NEL + 3) / 4 };
            ln2_k<<<(NEL + 3) / 4 + (NN + 3) / 4, 256, 0, stream>>>(L);
        }
    }
    // outputs already in d_out
}

// Round 22
// 1627.052 us; speedup vs baseline: 1.0259x; 1.0259x over previous
//
#include <hip/hip_runtime.h>
#include <math.h>

#define NN   10000      // nodes
#define DD   512        // node dim
#define NH   8          // node heads (DK=64)
#define NE   120000     // edges (global)
#define NEL  60000      // local edges
#define NLG  600000     // line-graph edges
#define ED   64         // edge dim (EH=8, EDK=8)
#define NEH  8
#define NL   4          // layers
#define QKVW 1536       // fused q|k|v row width

typedef __attribute__((ext_vector_type(8))) short bf16x8;
typedef __attribute__((ext_vector_type(8))) unsigned short u16x8;
typedef __attribute__((ext_vector_type(4))) float f32x4;

__device__ __forceinline__ unsigned short f2b(float f) {
    union { float f; unsigned u; } c; c.f = f;
    unsigned u = c.u;
    unsigned r = u + 0x7FFFu + ((u >> 16) & 1u);
    return (unsigned short)(r >> 16);
}
__device__ __forceinline__ float b2f(unsigned short b) {
    union { unsigned u; float f; } c; c.u = ((unsigned)b) << 16;
    return c.f;
}

// async global->LDS, 16B per lane; LDS dest is wave-uniform base + lane*16 (HW)
__device__ __forceinline__ void gl16(const unsigned short* g, unsigned short* l) {
    __builtin_amdgcn_global_load_lds(
        (const __attribute__((address_space(1))) unsigned int*)g,
        (__attribute__((address_space(3))) unsigned int*)l, 16, 0, 0);
}

// ---------------- fused init: castcopy + lgb init + el gather --------------
static __global__ __launch_bounds__(256)
void init_all_k(const float* __restrict__ x_in, const float* __restrict__ rel,
                const int* __restrict__ ef, const int* __restrict__ lidx,
                float* __restrict__ xbuf, unsigned short* __restrict__ xb,
                unsigned short* __restrict__ lgb,
                float* __restrict__ el, unsigned short* __restrict__ elb)
{
    long i = (long)blockIdx.x * 256 + threadIdx.x;
    const long n1 = (long)NN * DD, n2 = n1 + (long)NE * ED, n3 = n2 + (long)NEL * ED;
    if (i < n1) {
        float v = x_in[i]; xbuf[i] = v; xb[i] = f2b(v);
    } else if (i < n2) {
        long k = i - n1; int e = (int)(k >> 6), c = (int)(k & 63);
        lgb[k] = f2b(rel[(long)ef[e] * ED + c]);
    } else if (i < n3) {
        long k = i - n2; int r = (int)(k >> 6), c = (int)(k & 63);
        unsigned short b = f2b(rel[(long)ef[lidx[r]] * ED + c]);
        el[k] = b2f(b); elb[k] = b;
    }
}

// ---------------- fused weight transpose+cast (all 15 segments) ------------
#define NSEG 15
struct TT {
    const float* src[NSEG];
    unsigned short* dst[NSEG];
    long lstride[NSEG];
    int K[NSEG], Nn[NSEG], rowStride[NSEG], rowOff[NSEG], colOff[NSEG];
    int blkStart[NSEG];
};

static __global__ __launch_bounds__(256)
void ttrans_all_k(TT t) {
    const int bid = blockIdx.x;
    int s = 0;
    #pragma unroll
    for (int i = 1; i < NSEG; ++i) s += (bid >= t.blkStart[i]);
    const int local = bid - t.blkStart[s];
    const int K = t.K[s], N = t.Nn[s];
    const int nKb = K >> 5;
    const int perL = nKb * (N >> 5);
    const int l = local / perL;
    const int rem = local - l * perL;
    const int kt = (rem % nKb) * 32;
    const int nt = (rem / nKb) * 32;
    __shared__ float sm[32][33];
    const int tx = threadIdx.x & 31, ty = threadIdx.x >> 5;
    const float* ip = t.src[s] + (size_t)l * K * N;
    #pragma unroll
    for (int r = 0; r < 4; ++r)
        sm[ty + 8 * r][tx] = ip[(size_t)(kt + ty + 8 * r) * N + nt + tx];
    __syncthreads();
    unsigned short* op = t.dst[s] + (size_t)l * t.lstride[s];
    #pragma unroll
    for (int r = 0; r < 4; ++r) {
        int n = nt + ty + 8 * r;
        op[(size_t)(t.rowOff[s] + n) * t.rowStride[s] + t.colOff[s] + kt + tx] =
            f2b(sm[tx][ty + 8 * r]);
    }
}

// ---------------- fused bias prep ----------------
static __global__ __launch_bounds__(256)
void biases_k(const float* __restrict__ bq, const float* __restrict__ ndb,
              const float* __restrict__ eqb, const float* __restrict__ nsb,
              float* __restrict__ qkvb, float* __restrict__ kvb,
              float* __restrict__ qb2)
{
    int i = blockIdx.x * 256 + threadIdx.x;
    if (i < NL * QKVW) { int l = i / QKVW, c = i - l * QKVW; qkvb[i] = (c < 512) ? bq[l * 512 + c] : 0.0f; }
    if (i < NL * 128) kvb[i] = ndb[(i >> 7) * 64 + (i & 63)];
    if (i < NL * 64)  qb2[i] = eqb[i] + nsb[i];
}

// ---------------- CSR build (both graphs fused per stage) ------------------
static __global__ __launch_bounds__(256)
void zero2_k(int* __restrict__ gcnt, int* __restrict__ ecnt) {
    int i = blockIdx.x * 256 + threadIdx.x;
    if (i < NN)  gcnt[i] = 0;
    if (i < NEL) ecnt[i] = 0;
}

static __global__ __launch_bounds__(256)
void hist2_k(const int* __restrict__ gdst, const int* __restrict__ ldst,
             int* __restrict__ gcnt, int* __restrict__ ecnt) {
    int i = blockIdx.x * 256 + threadIdx.x;
    if (i < NE) atomicAdd(&gcnt[gdst[i]], 1);
    else if (i < NE + NLG) atomicAdd(&ecnt[ldst[i - NE]], 1);
}

static __global__ __launch_bounds__(256)
void scanA2_k(const int* __restrict__ gcnt, const int* __restrict__ ecnt,
              int* __restrict__ goff, int* __restrict__ eoff,
              int* __restrict__ bsum, int nbG) {
    __shared__ int sm[256];
    const int t = threadIdx.x;
    const bool isG = blockIdx.x < (unsigned)nbG;
    const int b = isG ? blockIdx.x : blockIdx.x - nbG;
    const int n = isG ? NN : NEL;
    const int* cnt = isG ? gcnt : ecnt;
    int* off = isG ? goff : eoff;
    int* bs = bsum + (isG ? 0 : 512);
    const int i = b * 256 + t;
    int v = (i < n) ? cnt[i] : 0;
    sm[t] = v; __syncthreads();
    int x = v;
    #pragma unroll
    for (int d = 1; d < 256; d <<= 1) {
        int y = (t >= d) ? sm[t - d] : 0;
        __syncthreads();
        x += y; sm[t] = x; __syncthreads();
    }
    if (i < n) off[i] = x - v;
    if (t == 255) bs[b] = x;
}

static __global__ __launch_bounds__(1024)
void scanB2_k(int* __restrict__ bsum, int nbG, int nbE) {
    __shared__ int sm[1024];
    const int t = threadIdx.x;
    int* bs = bsum + (blockIdx.x ? 512 : 0);
    const int nb = blockIdx.x ? nbE : nbG;
    int v = (t < nb) ? bs[t] : 0;
    sm[t] = v; __syncthreads();
    int x = v;
    #pragma unroll
    for (int d = 1; d < 1024; d <<= 1) {
        int y = (t >= d) ? sm[t - d] : 0;
        __syncthreads();
        x += y; sm[t] = x; __syncthreads();
    }
    if (t < nb) bs[t] = x - v;
}

static __global__ __launch_bounds__(256)
void scanC2_k(const int* __restrict__ bsum, int* __restrict__ goff,
              int* __restrict__ eoff, int* __restrict__ gcur,
              int* __restrict__ ecur, int nbG) {
    const bool isG = blockIdx.x < (unsigned)nbG;
    const int b = isG ? blockIdx.x : blockIdx.x - nbG;
    const int n = isG ? NN : NEL;
    int* off = isG ? goff : eoff;
    int* cur = isG ? gcur : ecur;
    const int* bs = bsum + (isG ? 0 : 512);
    int i = b * 256 + threadIdx.x;
    if (i < n) { int o = off[i] + bs[b]; off[i] = o; cur[i] = o; }
}

static __global__ __launch_bounds__(256)
void scatterpack_k(const int* __restrict__ gdst, const int* __restrict__ ldst,
                   const int* __restrict__ gsrc, const int* __restrict__ lsrc,
                   int* __restrict__ gcur, int* __restrict__ ecur,
                   int2* __restrict__ npack, int* __restrict__ esrc) {
    int i = blockIdx.x * 256 + threadIdx.x;
    if (i < NE) {
        int p = atomicAdd(&gcur[gdst[i]], 1);
        npack[p] = make_int2(i, gsrc[i]);
    } else if (i < NE + NLG) {
        int k = i - NE;
        int p = atomicAdd(&ecur[ldst[k]], 1);
        esrc[p] = lsrc[k];
    }
}

// ---------------- segmented bf16 MFMA GEMM (up to 3 independent GEMMs) -----
struct GSeg {
    const unsigned short* A;
    const unsigned short* A2;     // null => plain A[M,K]
    const int* idx2;
    const unsigned short* Bt;
    const float* bias;
    const unsigned short* addCb;  // may be null
    unsigned short* Cb;
    int M, K, Nc, K1, blkStart, gridX, doRelu;
};
struct GSegs { GSeg s[3]; int nseg; int total; };

static __global__ __launch_bounds__(256)
void gemmseg_k(GSegs g)
{
    __shared__ unsigned short Asl[64 * 64];
    __shared__ unsigned short Bsl[64 * 64];
    const int tid  = threadIdx.x;
    const int lane = tid & 63;
    const int wave = tid >> 6;
    const int wr = (wave >> 1) * 32;
    const int wc = (wave & 1) * 32;

    const int nwg = g.total;
    const int hw = blockIdx.x;
    const int q8 = nwg >> 3, r8 = nwg & 7;
    const int xcd = hw & 7, rest = hw >> 3;
    const int logical = (xcd < r8 ? xcd * (q8 + 1) : r8 * (q8 + 1) + (xcd - r8) * q8) + rest;

    int si = 0;
    #pragma unroll
    for (int i = 1; i < 3; ++i) si += (i < g.nseg && logical >= g.s[i].blkStart);
    const GSeg S = g.s[si];
    const int local = logical - S.blkStart;
    const int bm = (local / S.gridX) * 64;
    const int bn = (local % S.gridX) * 64;
    const int M = S.M, K = S.K, Nc = S.Nc, K1 = S.K1;

    const int rl8 = lane >> 3;
    const int sl8 = lane & 7;
    int ga[2]; long ia[2]; bool av[2]; int acw[2];
    int gb[2]; int bcw[2];
    #pragma unroll
    for (int c = 0; c < 2; ++c) {
        int ar = wave * 16 + c * 8 + rl8;
        ga[c] = bm + ar;
        av[c] = ga[c] < M;
        ia[c] = (S.A2 && av[c]) ? (long)S.idx2[ga[c]] : 0;
        acw[c] = (sl8 ^ (ar & 7)) * 8;
        int br = wave * 16 + c * 8 + rl8;
        gb[c] = bn + br;
        bcw[c] = (sl8 ^ (br & 7)) * 8;
    }

    auto stage = [&](int k0) {
        #pragma unroll
        for (int c = 0; c < 2; ++c) {
            const unsigned short* s;
            if (!S.A2)          s = S.A  + (long)ga[c] * K  + k0 + acw[c];
            else if (k0 < K1)   s = S.A  + (long)ga[c] * K1 + k0 + acw[c];
            else                s = S.A2 + ia[c] * DD + (k0 - K1) + acw[c];
            if (av[c]) gl16(s, Asl + (wave * 16 + c * 8) * 64);
            gl16(S.Bt + (long)gb[c] * K + k0 + bcw[c], Bsl + (wave * 16 + c * 8) * 64);
        }
    };

    f32x4 acc[2][2] = {};
    const int rbase = lane & 15;
    const int ks = lane >> 4;

    for (int k0 = 0; k0 < K; k0 += 64) {
        stage(k0);
        __syncthreads();
        #pragma unroll
        for (int h = 0; h < 2; ++h) {
            bf16x8 af[2], bfr[2];
            #pragma unroll
            for (int mi = 0; mi < 2; ++mi) {
                int r = wr + mi * 16 + rbase;
                int p = (h * 4 + ks) ^ (r & 7);
                af[mi] = *reinterpret_cast<const bf16x8*>(Asl + r * 64 + p * 8);
            }
            #pragma unroll
            for (int ni = 0; ni < 2; ++ni) {
                int r = wc + ni * 16 + rbase;
                int p = (h * 4 + ks) ^ (r & 7);
                bfr[ni] = *reinterpret_cast<const bf16x8*>(Bsl + r * 64 + p * 8);
            }
            #pragma unroll
            for (int mi = 0; mi < 2; ++mi)
                #pragma unroll
                for (int ni = 0; ni < 2; ++ni)
                    acc[mi][ni] = __builtin_amdgcn_mfma_f32_16x16x32_bf16(
                        af[mi], bfr[ni], acc[mi][ni], 0, 0, 0);
        }
        __syncthreads();
    }

    const int colBase = bn + wc + rbase;
    const int rowBase = bm + wr + ks * 4;
    #pragma unroll
    for (int mi = 0; mi < 2; ++mi) {
        #pragma unroll
        for (int j = 0; j < 4; ++j) {
            int r = rowBase + mi * 16 + j;
            if (r >= M) continue;
            long ro = (long)r * Nc;
            #pragma unroll
            for (int ni = 0; ni < 2; ++ni) {
                int cc = colBase + ni * 16;
                if (cc >= Nc) continue;
                float v = acc[mi][ni][j];
                if (S.bias)  v += S.bias[cc];
                if (S.doRelu) v = fmaxf(v, 0.0f);
                if (S.addCb) v += b2f(S.addCb[ro + cc]);
                S.Cb[ro + cc] = f2b(v);
            }
        }
    }
}

// ---------------- segmented LayerNorm (2 independent LNs) ----------------
struct LNSeg {
    const unsigned short* inb;
    const float* g; const float* b;
    float* out;                 // may be null
    unsigned short* outb;       // may be null
    unsigned short* out2b;      // may be null (scatter via idx2)
    const int* idx2;
    int Dw, nrows, blkStart;
};
struct LNSegs { LNSeg s[2]; };

static __global__ __launch_bounds__(256)
void ln2_k(LNSegs L)
{
    const int sidx = (blockIdx.x >= (unsigned)L.s[1].blkStart) ? 1 : 0;
    const LNSeg S = L.s[sidx];
    const int row = (blockIdx.x - S.blkStart) * 4 + (threadIdx.x >> 6);
    if (row >= S.nrows) return;
    const int lane = threadIdx.x & 63;
    const int per = S.Dw >> 6;
    float v[8];
    float s = 0.f;
    const unsigned short* rp = S.inb + (long)row * S.Dw;
    for (int i = 0; i < per; ++i) { v[i] = b2f(rp[i * 64 + lane]); s += v[i]; }
    #pragma unroll
    for (int off = 32; off; off >>= 1) s += __shfl_xor(s, off, 64);
    const float mu = s / (float)S.Dw;
    float var = 0.f;
    for (int i = 0; i < per; ++i) { float d = v[i] - mu; var += d * d; }
    #pragma unroll
    for (int off = 32; off; off >>= 1) var += __shfl_xor(var, off, 64);
    const float rstd = rsqrtf(var / (float)S.Dw + 1e-5f);
    for (int i = 0; i < per; ++i) {
        int c = i * 64 + lane;
        float o = (v[i] - mu) * rstd * S.g[c] + S.b[c];
        if (S.out)   S.out[(long)row * S.Dw + c] = o;
        if (S.outb)  S.outb[(long)row * S.Dw + c] = f2b(o);
        if (S.out2b) S.out2b[(long)S.idx2[row] * S.Dw + c] = f2b(o);
    }
}

// ---------------- node attention, CSR, 2-way unrolled (standalone) ---------
static __global__ __launch_bounds__(256)
void node_attn_csr_k(const unsigned short* __restrict__ qkv,
                     const unsigned short* __restrict__ lgb,
                     const int* __restrict__ goff, const int2* __restrict__ npack,
                     unsigned short* __restrict__ ob)
{
    int node = blockIdx.x * 4 + (threadIdx.x >> 6);
    if (node >= NN) return;
    const int lane = threadIdx.x & 63;
    float qv[8];
    {
        u16x8 q8 = *reinterpret_cast<const u16x8*>(qkv + (long)node * QKVW + lane * 8);
        #pragma unroll
        for (int i = 0; i < 8; ++i) qv[i] = b2f(q8[i]);
    }
    float wva[8] = {0.f, 0.f, 0.f, 0.f, 0.f, 0.f, 0.f, 0.f};
    float zac = 0.f;
    int j = goff[node];
    const int hi = (node + 1 < NN) ? goff[node + 1] : NE;
    const int eoffl = (lane & 7) * 8;

    for (; j + 2 <= hi; j += 2) {
        int2 pa = npack[j], pb = npack[j + 1];
        u16x8 kA = *reinterpret_cast<const u16x8*>(qkv + (long)pa.y * QKVW + 512 + lane * 8);
        u16x8 vA = *reinterpret_cast<const u16x8*>(qkv + (long)pa.y * QKVW + 1024 + lane * 8);
        u16x8 eA = *reinterpret_cast<const u16x8*>(lgb + (long)pa.x * ED + eoffl);
        u16x8 kB = *reinterpret_cast<const u16x8*>(qkv + (long)pb.y * QKVW + 512 + lane * 8);
        u16x8 vB = *reinterpret_cast<const u16x8*>(qkv + (long)pb.y * QKVW + 1024 + lane * 8);
        u16x8 eB = *reinterpret_cast<const u16x8*>(lgb + (long)pb.x * ED + eoffl);
        float edA[8], vvA[8], edB[8], vvB[8];
        float pA = 0.f, pB = 0.f;
        #pragma unroll
        for (int i = 0; i < 8; ++i) {
            edA[i] = b2f(eA[i]); vvA[i] = b2f(vA[i]);
            pA = fmaf(b2f(kA[i]) + edA[i], qv[i], pA);
            edB[i] = b2f(eB[i]); vvB[i] = b2f(vB[i]);
            pB = fmaf(b2f(kB[i]) + edB[i], qv[i], pB);
        }
        pA += __shfl_xor(pA, 1, 64); pA += __shfl_xor(pA, 2, 64); pA += __shfl_xor(pA, 4, 64);
        pB += __shfl_xor(pB, 1, 64); pB += __shfl_xor(pB, 2, 64); pB += __shfl_xor(pB, 4, 64);
        float wA = expf(fminf(fmaxf(pA * 0.125f, -10.0f), 10.0f));
        float wB = expf(fminf(fmaxf(pB * 0.125f, -10.0f), 10.0f));
        #pragma unroll
        for (int i = 0; i < 8; ++i) {
            wva[i] = fmaf(wA, vvA[i] + edA[i], wva[i]);
            wva[i] = fmaf(wB, vvB[i] + edB[i], wva[i]);
        }
        zac += wA + wB;
    }
    for (; j < hi; ++j) {
        int2 pa = npack[j];
        u16x8 kA = *reinterpret_cast<const u16x8*>(qkv + (long)pa.y * QKVW + 512 + lane * 8);
        u16x8 vA = *reinterpret_cast<const u16x8*>(qkv + (long)pa.y * QKVW + 1024 + lane * 8);
        u16x8 eA = *reinterpret_cast<const u16x8*>(lgb + (long)pa.x * ED + eoffl);
        float edA[8], vvA[8];
        float pA = 0.f;
        #pragma unroll
        for (int i = 0; i < 8; ++i) {
            edA[i] = b2f(eA[i]); vvA[i] = b2f(vA[i]);
            pA = fmaf(b2f(kA[i]) + edA[i], qv[i], pA);
        }
        pA += __shfl_xor(pA, 1, 64); pA += __shfl_xor(pA, 2, 64); pA += __shfl_xor(pA, 4, 64);
        float wA = expf(fminf(fmaxf(pA * 0.125f, -10.0f), 10.0f));
        #pragma unroll
        for (int i = 0; i < 8; ++i) wva[i] = fmaf(wA, vvA[i] + edA[i], wva[i]);
        zac += wA;
    }
    const float inv = 1.0f / fmaxf(zac, 1e-9f);
    u16x8 o8;
    #pragma unroll
    for (int i = 0; i < 8; ++i) o8[i] = f2b(wva[i] * inv);
    *reinterpret_cast<u16x8*>(ob + (long)node * DD + lane * 8) = o8;
}

// ---------------- line-graph attention, CSR, (edge,head)-per-lane ----------
static __global__ __launch_bounds__(256)
void lg_attn_csr_k(const unsigned short* __restrict__ qeb,
                   const unsigned short* __restrict__ keve,
                   const int* __restrict__ eoff, const int* __restrict__ esrc,
                   unsigned short* __restrict__ oeb)
{
    int d = blockIdx.x * 4 + (threadIdx.x >> 6);
    if (d >= NEL) return;
    const int lane = threadIdx.x & 63;
    const int he = lane & 7;
    const int ee = lane >> 3;
    const int hd = lane >> 3;
    float qv8[8];
    {
        u16x8 q8 = *reinterpret_cast<const u16x8*>(qeb + (long)d * ED + he * 8);
        #pragma unroll
        for (int i = 0; i < 8; ++i) qv8[i] = b2f(q8[i]);
    }
    const float qvd = b2f(qeb[(long)d * ED + lane]);
    float oa = 0.f, zac = 0.f;
    int j = eoff[d];
    const int hi = (d + 1 < NEL) ? eoff[d + 1] : NLG;

    for (; j + 8 <= hi; j += 8) {
        int sMine = esrc[j + ee];
        u16x8 k8 = *reinterpret_cast<const u16x8*>(keve + (long)sMine * 128 + he * 8);
        float p = 0.f;
        #pragma unroll
        for (int i = 0; i < 8; ++i) p = fmaf(b2f(k8[i]), qv8[i], p);
        float w = expf(fminf(fmaxf(p * 0.35355339059327373f, -10.0f), 10.0f));
        #pragma unroll
        for (int u = 0; u < 8; ++u) {
            float wu = __shfl(w, u * 8 + hd, 64);
            int   su = esrc[j + u];
            float vv = b2f(keve[(long)su * 128 + 64 + lane]);
            oa = fmaf(wu, vv, oa);
            zac += wu;
        }
    }
    for (; j < hi; ++j) {
        int s = esrc[j];
        float kv = b2f(keve[(long)s * 128 + lane]);
        float vv = b2f(keve[(long)s * 128 + 64 + lane]);
        float p = kv * qvd;
        p += __shfl_xor(p, 1, 64); p += __shfl_xor(p, 2, 64); p += __shfl_xor(p, 4, 64);
        float w = expf(fminf(fmaxf(p * 0.35355339059327373f, -10.0f), 10.0f));
        oa = fmaf(w, vv, oa);
        zac += w;
    }
    oeb[(long)d * ED + lane] = f2b(oa / fmaxf(zac, 1e-9f));
}

// ---------------- host ----------------
extern "C" void kernel_launch(void* const* d_in, const int* in_sizes, int n_in,
                              void* d_out, int out_size, void* d_ws, size_t ws_size,
                              hipStream_t stream)
{
    const float* x_in  = (const float*)d_in[0];
    const float* rel   = (const float*)d_in[1];
    const float* Wq    = (const float*)d_in[2];
    const float* bq    = (const float*)d_in[3];
    const float* Wk    = (const float*)d_in[4];
    const float* Wv    = (const float*)d_in[5];
    const float* Wo    = (const float*)d_in[6];
    const float* bo    = (const float*)d_in[7];
    const float* ln1g  = (const float*)d_in[8];
    const float* ln1b  = (const float*)d_in[9];
    const float* F1    = (const float*)d_in[10];
    const float* f1b   = (const float*)d_in[11];
    const float* F2    = (const float*)d_in[12];
    const float* f2b_  = (const float*)d_in[13];
    const float* ln2g  = (const float*)d_in[14];
    const float* ln2b  = (const float*)d_in[15];
    const float* Eq    = (const float*)d_in[16];
    const float* eqb   = (const float*)d_in[17];
    const float* Ek    = (const float*)d_in[18];
    const float* Ev    = (const float*)d_in[19];
    const float* Eo    = (const float*)d_in[20];
    const float* eob   = (const float*)d_in[21];
    const float* Ns    = (const float*)d_in[22];
    const float* nsb   = (const float*)d_in[23];
    const float* Nd    = (const float*)d_in[24];
    const float* ndb   = (const float*)d_in[25];
    const float* eln1g = (const float*)d_in[26];
    const float* eln1b = (const float*)d_in[27];
    const float* G1    = (const float*)d_in[28];
    const float* g1b   = (const float*)d_in[29];
    const float* G2    = (const float*)d_in[30];
    const float* g2b   = (const float*)d_in[31];
    const float* eln2g = (const float*)d_in[32];
    const float* eln2b = (const float*)d_in[33];
    const int* edge_feat   = (const int*)d_in[34];
    const int* local_index = (const int*)d_in[35];
    const int* src_ids     = (const int*)d_in[36];
    const int* dst_ids     = (const int*)d_in[37];
    const int* g_src       = (const int*)d_in[38];
    const int* g_dst       = (const int*)d_in[39];
    const int* lg_src      = (const int*)d_in[40];
    const int* lg_dst      = (const int*)d_in[41];

    // outputs live in d_out
    float* xbuf = (float*)d_out;                   // (NN, DD)
    float* el   = xbuf + (size_t)NN * DD;          // (NEL, ED)

    // ---- workspace layout ----
    float* W = (float*)d_ws;
    size_t off = 0;
    auto alloc = [&](size_t n) { float* p = W + off; off += (n + 63) & ~(size_t)63; return p; };
    float* qkvb = alloc((size_t)NL * QKVW);
    float* kvb  = alloc((size_t)NL * 128);
    float* qb2  = alloc((size_t)NL * ED);

    unsigned short* bp = (unsigned short*)(W + off);
    size_t boff = 0;
    auto balloc = [&](size_t n) { unsigned short* p = bp + boff; boff += (n + 63) & ~(size_t)63; return p; };
    unsigned short* lgb = balloc((size_t)NE * ED);
    unsigned short* xb  = balloc((size_t)NN * DD);
    unsigned short* qkv = balloc((size_t)NN * QKVW);
    // keve, qeb, t0b contiguous: gfe (edge-FFN intermediate, 15.36M) aliases
    // this region (all three dead when gfe is live).
    unsigned short* keve = balloc((size_t)NEL * 128);
    unsigned short* qeb  = balloc((size_t)NEL * ED);
    unsigned short* t0b  = balloc((size_t)NN * DD);
    unsigned short* gfe  = keve;                      // NEL*4*ED = 15.36M alias
    unsigned short* elb = balloc((size_t)NEL * ED);
    unsigned short* e1b = balloc((size_t)NEL * ED);
    unsigned short* heb = balloc((size_t)NEL * ED);
    unsigned short* fgb = balloc((size_t)NN * 4 * DD);
    unsigned short* t2b = balloc((size_t)NEL * ED);   // pre-LN he
    unsigned short* t3b = balloc((size_t)NEL * ED);   // pre-LN edge out
    unsigned short* xpb = balloc((size_t)NN * DD);    // pre-LN x
    unsigned short* hb   = qkv;                       // safe: dead before next QKV write
    unsigned short* ob   = fgb;                       // safe: consumed before G1/F1 write
    unsigned short* WqkvT = balloc((size_t)NL * QKVW * DD);
    unsigned short* WoT  = balloc((size_t)NL * DD * DD);
    unsigned short* F1T  = balloc((size_t)NL * DD * 4 * DD);
    unsigned short* F2T  = balloc((size_t)NL * 4 * DD * DD);
    unsigned short* KVET = balloc((size_t)NL * 128 * 576);
    unsigned short* QET  = balloc((size_t)NL * 64 * 576);
    unsigned short* EoT  = balloc((size_t)NL * ED * ED);
    unsigned short* G1T  = balloc((size_t)NL * ED * 4 * ED);
    unsigned short* G2T  = balloc((size_t)NL * 4 * ED * ED);
    int* ip = (int*)(bp + ((boff + 63) & ~(size_t)63));
    size_t ioff = 0;
    auto ialloc = [&](size_t n) { int* p = ip + ioff; ioff += (n + 63) & ~(size_t)63; return p; };
    int* gcnt = ialloc(NN);
    int* goff = ialloc(NN);
    int* gcur = ialloc(NN);
    int2* npack = (int2*)ialloc(2 * (size_t)NE);
    int* ecnt = ialloc(NEL);
    int* eoff = ialloc(NEL);
    int* ecur = ialloc(NEL);
    int* esrc = ialloc(NLG);
    int* bsum = ialloc(1024);

    // ---- fused weight prep ----
    TT tt;
    int bc = 0, si = 0;
    auto seg = [&](const float* src, unsigned short* dst, int K, int N,
                   long lstride, int rowStride, int rowOff, int colOff) {
        tt.src[si] = src; tt.dst[si] = dst; tt.lstride[si] = lstride;
        tt.K[si] = K; tt.Nn[si] = N; tt.rowStride[si] = rowStride;
        tt.rowOff[si] = rowOff; tt.colOff[si] = colOff;
        tt.blkStart[si] = bc;
        bc += (K / 32) * (N / 32) * NL;
        ++si;
    };
    seg(Wq, WqkvT, 512, 512, (long)QKVW * DD, DD, 0, 0);
    seg(Wk, WqkvT, 512, 512, (long)QKVW * DD, DD, 512, 0);
    seg(Wv, WqkvT, 512, 512, (long)QKVW * DD, DD, 1024, 0);
    seg(Wo, WoT, 512, 512, (long)DD * DD, DD, 0, 0);
    seg(F1, F1T, 512, 2048, (long)DD * 4 * DD, DD, 0, 0);
    seg(F2, F2T, 2048, 512, (long)4 * DD * DD, 4 * DD, 0, 0);
    seg(Ek, KVET, 64, 64, (long)128 * 576, 576, 0, 0);
    seg(Nd, KVET, 512, 64, (long)128 * 576, 576, 0, 64);
    seg(Ev, KVET, 64, 64, (long)128 * 576, 576, 64, 0);
    seg(Nd, KVET, 512, 64, (long)128 * 576, 576, 64, 64);
    seg(Eq, QET, 64, 64, (long)64 * 576, 576, 0, 0);
    seg(Ns, QET, 512, 64, (long)64 * 576, 576, 0, 64);
    seg(Eo, EoT, 64, 64, (long)ED * ED, ED, 0, 0);
    seg(G1, G1T, 64, 256, (long)ED * 4 * ED, ED, 0, 0);
    seg(G2, G2T, 256, 64, (long)4 * ED * ED, 4 * ED, 0, 0);
    ttrans_all_k<<<bc, 256, 0, stream>>>(tt);
    biases_k<<<(NL * QKVW + 255) / 256, 256, 0, stream>>>(bq, ndb, eqb, nsb, qkvb, kvb, qb2);

    // ---- CSR build ----
    const int nbG = (NN + 255) / 256, nbE = (NEL + 255) / 256;
    zero2_k<<<nbE, 256, 0, stream>>>(gcnt, ecnt);
    hist2_k<<<(NE + NLG + 255) / 256, 256, 0, stream>>>(g_dst, lg_dst, gcnt, ecnt);
    scanA2_k<<<nbG + nbE, 256, 0, stream>>>(gcnt, ecnt, goff, eoff, bsum, nbG);
    scanB2_k<<<2, 1024, 0, stream>>>(bsum, nbG, nbE);
    scanC2_k<<<nbG + nbE, 256, 0, stream>>>(bsum, goff, eoff, gcur, ecur, nbG);
    scatterpack_k<<<(NE + NLG + 255) / 256, 256, 0, stream>>>(
        g_dst, lg_dst, g_src, lg_src, gcur, ecur, npack, esrc);

    // ---- fused init ----
    {
        long tot = (long)NN * DD + (long)NE * ED + (long)NEL * ED;
        init_all_k<<<(int)((tot + 255) / 256), 256, 0, stream>>>(
            x_in, rel, edge_feat, local_index, xbuf, xb, lgb, el, elb);
    }

    const int rQ = (NN + 63) / 64;    // 157
    const int rE = (NEL + 63) / 64;   // 938

    for (int i = 0; i < NL; ++i) {
        size_t oD2 = (size_t)i * DD * DD, oE2 = (size_t)i * ED * ED;

        // ---- merged {QKV | KVE | QE} ----
        {
            GSegs G;
            G.s[0] = { xb, nullptr, nullptr, WqkvT + (size_t)i * QKVW * DD,
                       qkvb + (size_t)i * QKVW, nullptr, qkv,
                       NN, DD, QKVW, 0, 0, QKVW / 64, 0 };
            int b0 = (QKVW / 64) * rQ;
            G.s[1] = { elb, xb, dst_ids, KVET + (size_t)i * 128 * 576,
                       kvb + (size_t)i * 128, nullptr, keve,
                       NEL, 576, 128, 64, b0, 2, 0 };
            int b1 = b0 + 2 * rE;
            G.s[2] = { elb, xb, src_ids, QET + (size_t)i * 64 * 576,
                       qb2 + (size_t)i * 64, nullptr, qeb,
                       NEL, 576, 64, 64, b1, 1, 0 };
            G.nseg = 3; G.total = b1 + rE;
            gemmseg_k<<<G.total, 256, 0, stream>>>(G);
        }

        // ---- attentions (separate kernels: different register classes) ----
        node_attn_csr_k<<<NN / 4, 256, 0, stream>>>(qkv, lgb, goff, npack, ob);
        lg_attn_csr_k<<<NEL / 4, 256, 0, stream>>>(qeb, keve, eoff, esrc, e1b);

        // ---- merged {Wo | Eo} ----
        {
            GSegs G;
            G.s[0] = { ob, nullptr, nullptr, WoT + oD2,
                       bo + (size_t)i * DD, xb, t0b,
                       NN, DD, DD, 0, 0, DD / 64, 0 };
            int b0 = (DD / 64) * rQ;
            G.s[1] = { e1b, nullptr, nullptr, EoT + oE2,
                       eob + (size_t)i * ED, elb, t2b,
                       NEL, ED, ED, 0, b0, 1, 0 };
            G.s[2] = G.s[1];
            G.nseg = 2; G.total = b0 + rE;
            gemmseg_k<<<G.total, 256, 0, stream>>>(G);
        }

        // ---- merged mid LNs {h | he} ----
        {
            LNSegs L;
            L.s[0] = { t0b, ln1g + (size_t)i * DD, ln1b + (size_t)i * DD,
                       nullptr, hb, nullptr, nullptr, DD, NN, 0 };
            L.s[1] = { t2b, eln1g + (size_t)i * ED, eln1b + (size_t)i * ED,
                       nullptr, heb, nullptr, nullptr, ED, NEL, (NN + 3) / 4 };
            ln2_k<<<(NN + 3) / 4 + (NEL + 3) / 4, 256, 0, stream>>>(L);
        }

        // ---- merged {G1 | F1} (relu) ----
        {
            GSegs G;
            G.s[0] = { heb, nullptr, nullptr, G1T + (size_t)i * ED * 4 * ED,
                       g1b + (size_t)i * 4 * ED, nullptr, gfe,
                       NEL, ED, 4 * ED, 0, 0, (4 * ED) / 64, 1 };
            int b0 = ((4 * ED) / 64) * rE;
            G.s[1] = { hb, nullptr, nullptr, F1T + (size_t)i * DD * 4 * DD,
                       f1b + (size_t)i * 4 * DD, nullptr, fgb,
                       NN, DD, 4 * DD, 0, b0, (4 * DD) / 64, 1 };
            G.s[2] = G.s[1];
            G.nseg = 2; G.total = b0 + ((4 * DD) / 64) * rQ;
            gemmseg_k<<<G.total, 256, 0, stream>>>(G);
        }

        // ---- merged {G2 | F2} ----
        {
            GSegs G;
            G.s[0] = { gfe, nullptr, nullptr, G2T + (size_t)i * 4 * ED * ED,
                       g2b + (size_t)i * ED, heb, t3b,
                       NEL, 4 * ED, ED, 0, 0, 1, 0 };
            int b0 = rE;
            G.s[1] = { fgb, nullptr, nullptr, F2T + (size_t)i * 4 * DD * DD,
                       f2b_ + (size_t)i * DD, hb, xpb,
                       NN, 4 * DD, DD, 0, b0, DD / 64, 0 };
            G.s[2] = G.s[1];
            G.nseg = 2; G.total = b0 + (DD / 64) * rQ;
            gemmseg_k<<<G.total, 256, 0, stream>>>(G);
        }

        // ---- merged final LNs {edge out | node out} ----
        {
            LNSegs L;
            L.s[0] = { t3b, eln2g + (size_t)i * ED, eln2b + (size_t)i * ED,
                       el, elb, lgb, local_index, ED, NEL, 0 };
            L.s[1] = { xpb, ln2g + (size_t)i * DD, ln2b + (size_t)i * DD,
                       xbuf, xb, nullptr, nullptr, DD, NN, (NEL + 3) / 4 };
            ln2_k<<<(NEL + 3) / 4 + (NN + 3) / 4, 256, 0, stream>>>(L);
        }
    }
    // outputs already in d_out
}

// Round 23
// 1576.104 us; speedup vs baseline: 1.0590x; 1.0323x over previous
//
#include <hip/hip_runtime.h>
#include <math.h>

#define NN   10000      // nodes
#define DD   512        // node dim
#define NH   8          // node heads (DK=64)
#define NE   120000     // edges (global)
#define NEL  60000      // local edges
#define NLG  600000     // line-graph edges
#define ED   64         // edge dim (EH=8, EDK=8)
#define NEH  8
#define NL   4          // layers
#define QKVW 1536       // fused q|k|v row width

typedef __attribute__((ext_vector_type(8))) short bf16x8;
typedef __attribute__((ext_vector_type(8))) unsigned short u16x8;
typedef __attribute__((ext_vector_type(4))) float f32x4;

__device__ __forceinline__ unsigned short f2b(float f) {
    union { float f; unsigned u; } c; c.f = f;
    unsigned u = c.u;
    unsigned r = u + 0x7FFFu + ((u >> 16) & 1u);
    return (unsigned short)(r >> 16);
}
__device__ __forceinline__ float b2f(unsigned short b) {
    union { unsigned u; float f; } c; c.u = ((unsigned)b) << 16;
    return c.f;
}

// async global->LDS, 16B per lane; LDS dest is wave-uniform base + lane*16 (HW)
__device__ __forceinline__ void gl16(const unsigned short* g, unsigned short* l) {
    __builtin_amdgcn_global_load_lds(
        (const __attribute__((address_space(1))) unsigned int*)g,
        (__attribute__((address_space(3))) unsigned int*)l, 16, 0, 0);
}

// ---------------- fused init: castcopy + lgb init + el gather --------------
static __global__ __launch_bounds__(256)
void init_all_k(const float* __restrict__ x_in, const float* __restrict__ rel,
                const int* __restrict__ ef, const int* __restrict__ lidx,
                float* __restrict__ xbuf, unsigned short* __restrict__ xb,
                unsigned short* __restrict__ lgb,
                float* __restrict__ el, unsigned short* __restrict__ elb)
{
    long i = (long)blockIdx.x * 256 + threadIdx.x;
    const long n1 = (long)NN * DD, n2 = n1 + (long)NE * ED, n3 = n2 + (long)NEL * ED;
    if (i < n1) {
        float v = x_in[i]; xbuf[i] = v; xb[i] = f2b(v);
    } else if (i < n2) {
        long k = i - n1; int e = (int)(k >> 6), c = (int)(k & 63);
        lgb[k] = f2b(rel[(long)ef[e] * ED + c]);
    } else if (i < n3) {
        long k = i - n2; int r = (int)(k >> 6), c = (int)(k & 63);
        unsigned short b = f2b(rel[(long)ef[lidx[r]] * ED + c]);
        el[k] = b2f(b); elb[k] = b;
    }
}

// ---------------- fused weight transpose+cast (all 15 segments) ------------
#define NSEG 15
struct TT {
    const float* src[NSEG];
    unsigned short* dst[NSEG];
    long lstride[NSEG];
    int K[NSEG], Nn[NSEG], rowStride[NSEG], rowOff[NSEG], colOff[NSEG];
    int blkStart[NSEG];
};

static __global__ __launch_bounds__(256)
void ttrans_all_k(TT t) {
    const int bid = blockIdx.x;
    int s = 0;
    #pragma unroll
    for (int i = 1; i < NSEG; ++i) s += (bid >= t.blkStart[i]);
    const int local = bid - t.blkStart[s];
    const int K = t.K[s], N = t.Nn[s];
    const int nKb = K >> 5;
    const int perL = nKb * (N >> 5);
    const int l = local / perL;
    const int rem = local - l * perL;
    const int kt = (rem % nKb) * 32;
    const int nt = (rem / nKb) * 32;
    __shared__ float sm[32][33];
    const int tx = threadIdx.x & 31, ty = threadIdx.x >> 5;
    const float* ip = t.src[s] + (size_t)l * K * N;
    #pragma unroll
    for (int r = 0; r < 4; ++r)
        sm[ty + 8 * r][tx] = ip[(size_t)(kt + ty + 8 * r) * N + nt + tx];
    __syncthreads();
    unsigned short* op = t.dst[s] + (size_t)l * t.lstride[s];
    #pragma unroll
    for (int r = 0; r < 4; ++r) {
        int n = nt + ty + 8 * r;
        op[(size_t)(t.rowOff[s] + n) * t.rowStride[s] + t.colOff[s] + kt + tx] =
            f2b(sm[tx][ty + 8 * r]);
    }
}

// ---------------- fused bias prep ----------------
static __global__ __launch_bounds__(256)
void biases_k(const float* __restrict__ bq, const float* __restrict__ ndb,
              const float* __restrict__ eqb, const float* __restrict__ nsb,
              float* __restrict__ qkvb, float* __restrict__ kvb,
              float* __restrict__ qb2)
{
    int i = blockIdx.x * 256 + threadIdx.x;
    if (i < NL * QKVW) { int l = i / QKVW, c = i - l * QKVW; qkvb[i] = (c < 512) ? bq[l * 512 + c] : 0.0f; }
    if (i < NL * 128) kvb[i] = ndb[(i >> 7) * 64 + (i & 63)];
    if (i < NL * 64)  qb2[i] = eqb[i] + nsb[i];
}

// ---------------- CSR build (both graphs fused per stage) ------------------
static __global__ __launch_bounds__(256)
void zero2_k(int* __restrict__ gcnt, int* __restrict__ ecnt) {
    int i = blockIdx.x * 256 + threadIdx.x;
    if (i < NN)  gcnt[i] = 0;
    if (i < NEL) ecnt[i] = 0;
}

static __global__ __launch_bounds__(256)
void hist2_k(const int* __restrict__ gdst, const int* __restrict__ ldst,
             int* __restrict__ gcnt, int* __restrict__ ecnt) {
    int i = blockIdx.x * 256 + threadIdx.x;
    if (i < NE) atomicAdd(&gcnt[gdst[i]], 1);
    else if (i < NE + NLG) atomicAdd(&ecnt[ldst[i - NE]], 1);
}

static __global__ __launch_bounds__(256)
void scanA2_k(const int* __restrict__ gcnt, const int* __restrict__ ecnt,
              int* __restrict__ goff, int* __restrict__ eoff,
              int* __restrict__ bsum, int nbG) {
    __shared__ int sm[256];
    const int t = threadIdx.x;
    const bool isG = blockIdx.x < (unsigned)nbG;
    const int b = isG ? blockIdx.x : blockIdx.x - nbG;
    const int n = isG ? NN : NEL;
    const int* cnt = isG ? gcnt : ecnt;
    int* off = isG ? goff : eoff;
    int* bs = bsum + (isG ? 0 : 512);
    const int i = b * 256 + t;
    int v = (i < n) ? cnt[i] : 0;
    sm[t] = v; __syncthreads();
    int x = v;
    #pragma unroll
    for (int d = 1; d < 256; d <<= 1) {
        int y = (t >= d) ? sm[t - d] : 0;
        __syncthreads();
        x += y; sm[t] = x; __syncthreads();
    }
    if (i < n) off[i] = x - v;
    if (t == 255) bs[b] = x;
}

static __global__ __launch_bounds__(1024)
void scanB2_k(int* __restrict__ bsum, int nbG, int nbE) {
    __shared__ int sm[1024];
    const int t = threadIdx.x;
    int* bs = bsum + (blockIdx.x ? 512 : 0);
    const int nb = blockIdx.x ? nbE : nbG;
    int v = (t < nb) ? bs[t] : 0;
    sm[t] = v; __syncthreads();
    int x = v;
    #pragma unroll
    for (int d = 1; d < 1024; d <<= 1) {
        int y = (t >= d) ? sm[t - d] : 0;
        __syncthreads();
        x += y; sm[t] = x; __syncthreads();
    }
    if (t < nb) bs[t] = x - v;
}

static __global__ __launch_bounds__(256)
void scanC2_k(const int* __restrict__ bsum, int* __restrict__ goff,
              int* __restrict__ eoff, int* __restrict__ gcur,
              int* __restrict__ ecur, int nbG) {
    const bool isG = blockIdx.x < (unsigned)nbG;
    const int b = isG ? blockIdx.x : blockIdx.x - nbG;
    const int n = isG ? NN : NEL;
    int* off = isG ? goff : eoff;
    int* cur = isG ? gcur : ecur;
    const int* bs = bsum + (isG ? 0 : 512);
    int i = b * 256 + threadIdx.x;
    if (i < n) { int o = off[i] + bs[b]; off[i] = o; cur[i] = o; }
}

// fused scatter+pack: write final payloads directly
static __global__ __launch_bounds__(256)
void scatterpack_k(const int* __restrict__ gdst, const int* __restrict__ ldst,
                   const int* __restrict__ gsrc, const int* __restrict__ lsrc,
                   int* __restrict__ gcur, int* __restrict__ ecur,
                   int2* __restrict__ npack, int* __restrict__ esrc) {
    int i = blockIdx.x * 256 + threadIdx.x;
    if (i < NE) {
        int p = atomicAdd(&gcur[gdst[i]], 1);
        npack[p] = make_int2(i, gsrc[i]);
    } else if (i < NE + NLG) {
        int k = i - NE;
        int p = atomicAdd(&ecur[ldst[k]], 1);
        esrc[p] = lsrc[k];
    }
}

// ---------------- segmented bf16 MFMA GEMM (up to 3 independent GEMMs) -----
// Proven 64x64/BK=64/single-buffered body; block table selects segment.
// Segment outputs MUST be disjoint (concurrent execution).
struct GSeg {
    const unsigned short* A;
    const unsigned short* A2;     // null => plain A[M,K]
    const int* idx2;
    const unsigned short* Bt;
    const float* bias;
    const unsigned short* addCb;  // may be null
    unsigned short* Cb;
    int M, K, Nc, K1, blkStart, gridX;
};
struct GSegs { GSeg s[3]; int nseg; int total; };

static __global__ __launch_bounds__(256)
void gemmseg_k(GSegs g)
{
    __shared__ unsigned short Asl[64 * 64];
    __shared__ unsigned short Bsl[64 * 64];
    const int tid  = threadIdx.x;
    const int lane = tid & 63;
    const int wave = tid >> 6;
    const int wr = (wave >> 1) * 32;
    const int wc = (wave & 1) * 32;

    // XCD-aware bijective block swizzle (m204) over the combined grid
    const int nwg = g.total;
    const int hw = blockIdx.x;
    const int q8 = nwg >> 3, r8 = nwg & 7;
    const int xcd = hw & 7, rest = hw >> 3;
    const int logical = (xcd < r8 ? xcd * (q8 + 1) : r8 * (q8 + 1) + (xcd - r8) * q8) + rest;

    int si = 0;
    #pragma unroll
    for (int i = 1; i < 3; ++i) si += (i < g.nseg && logical >= g.s[i].blkStart);
    const GSeg S = g.s[si];
    const int local = logical - S.blkStart;
    const int bm = (local / S.gridX) * 64;
    const int bn = (local % S.gridX) * 64;
    const int M = S.M, K = S.K, Nc = S.Nc, K1 = S.K1;

    const int rl8 = lane >> 3;
    const int sl8 = lane & 7;
    int ga[2]; long ia[2]; bool av[2]; int acw[2];
    int gb[2]; int bcw[2];
    #pragma unroll
    for (int c = 0; c < 2; ++c) {
        int ar = wave * 16 + c * 8 + rl8;
        ga[c] = bm + ar;
        av[c] = ga[c] < M;
        ia[c] = (S.A2 && av[c]) ? (long)S.idx2[ga[c]] : 0;
        acw[c] = (sl8 ^ (ar & 7)) * 8;
        int br = wave * 16 + c * 8 + rl8;
        gb[c] = bn + br;
        bcw[c] = (sl8 ^ (br & 7)) * 8;
    }

    auto stage = [&](int k0) {
        #pragma unroll
        for (int c = 0; c < 2; ++c) {
            const unsigned short* s;
            if (!S.A2)          s = S.A  + (long)ga[c] * K  + k0 + acw[c];
            else if (k0 < K1)   s = S.A  + (long)ga[c] * K1 + k0 + acw[c];
            else                s = S.A2 + ia[c] * DD + (k0 - K1) + acw[c];
            if (av[c]) gl16(s, Asl + (wave * 16 + c * 8) * 64);
            gl16(S.Bt + (long)gb[c] * K + k0 + bcw[c], Bsl + (wave * 16 + c * 8) * 64);
        }
    };

    f32x4 acc[2][2] = {};
    const int rbase = lane & 15;
    const int ks = lane >> 4;

    for (int k0 = 0; k0 < K; k0 += 64) {
        stage(k0);
        __syncthreads();
        #pragma unroll
        for (int h = 0; h < 2; ++h) {
            bf16x8 af[2], bfr[2];
            #pragma unroll
            for (int mi = 0; mi < 2; ++mi) {
                int r = wr + mi * 16 + rbase;
                int p = (h * 4 + ks) ^ (r & 7);
                af[mi] = *reinterpret_cast<const bf16x8*>(Asl + r * 64 + p * 8);
            }
            #pragma unroll
            for (int ni = 0; ni < 2; ++ni) {
                int r = wc + ni * 16 + rbase;
                int p = (h * 4 + ks) ^ (r & 7);
                bfr[ni] = *reinterpret_cast<const bf16x8*>(Bsl + r * 64 + p * 8);
            }
            #pragma unroll
            for (int mi = 0; mi < 2; ++mi)
                #pragma unroll
                for (int ni = 0; ni < 2; ++ni)
                    acc[mi][ni] = __builtin_amdgcn_mfma_f32_16x16x32_bf16(
                        af[mi], bfr[ni], acc[mi][ni], 0, 0, 0);
        }
        __syncthreads();
    }

    const int colBase = bn + wc + rbase;
    const int rowBase = bm + wr + ks * 4;
    #pragma unroll
    for (int mi = 0; mi < 2; ++mi) {
        #pragma unroll
        for (int j = 0; j < 4; ++j) {
            int r = rowBase + mi * 16 + j;
            if (r >= M) continue;
            long ro = (long)r * Nc;
            #pragma unroll
            for (int ni = 0; ni < 2; ++ni) {
                int cc = colBase + ni * 16;
                if (cc >= Nc) continue;
                float v = acc[mi][ni][j];
                if (S.bias)  v += S.bias[cc];
                if (S.addCb) v += b2f(S.addCb[ro + cc]);
                S.Cb[ro + cc] = f2b(v);
            }
        }
    }
}

// ---------------- standalone bf16 MFMA GEMM (same body) --------------------
static __global__ __launch_bounds__(256)
void gemm_bf16_k(const unsigned short* __restrict__ A,
                 const unsigned short* __restrict__ A2, const int* __restrict__ idx2,
                 const unsigned short* __restrict__ Bt, const float* __restrict__ bias,
                 const float* __restrict__ addC, const unsigned short* __restrict__ addCb,
                 float* __restrict__ C, unsigned short* __restrict__ Cb,
                 int M, int K, int Nc, int doRelu, int K1)
{
    __shared__ unsigned short Asl[64 * 64];
    __shared__ unsigned short Bsl[64 * 64];
    const int tid  = threadIdx.x;
    const int lane = tid & 63;
    const int wave = tid >> 6;
    const int wr = (wave >> 1) * 32;
    const int wc = (wave & 1) * 32;

    const int nwg = gridDim.x * gridDim.y;
    const int hw = blockIdx.y * gridDim.x + blockIdx.x;
    const int q8 = nwg >> 3, r8 = nwg & 7;
    const int xcd = hw & 7, rest = hw >> 3;
    const int logical = (xcd < r8 ? xcd * (q8 + 1) : r8 * (q8 + 1) + (xcd - r8) * q8) + rest;
    const int bm = (logical / gridDim.x) * 64;
    const int bn = (logical % gridDim.x) * 64;

    const int rl8 = lane >> 3;
    const int sl8 = lane & 7;
    int ga[2]; long ia[2]; bool av[2]; int acw[2];
    int gb[2]; int bcw[2];
    #pragma unroll
    for (int c = 0; c < 2; ++c) {
        int ar = wave * 16 + c * 8 + rl8;
        ga[c] = bm + ar;
        av[c] = ga[c] < M;
        ia[c] = (A2 && av[c]) ? (long)idx2[ga[c]] : 0;
        acw[c] = (sl8 ^ (ar & 7)) * 8;
        int br = wave * 16 + c * 8 + rl8;
        gb[c] = bn + br;
        bcw[c] = (sl8 ^ (br & 7)) * 8;
    }

    auto stage = [&](int k0) {
        #pragma unroll
        for (int c = 0; c < 2; ++c) {
            const unsigned short* s;
            if (!A2)            s = A  + (long)ga[c] * K  + k0 + acw[c];
            else if (k0 < K1)   s = A  + (long)ga[c] * K1 + k0 + acw[c];
            else                s = A2 + ia[c] * DD + (k0 - K1) + acw[c];
            if (av[c]) gl16(s, Asl + (wave * 16 + c * 8) * 64);
            gl16(Bt + (long)gb[c] * K + k0 + bcw[c], Bsl + (wave * 16 + c * 8) * 64);
        }
    };

    f32x4 acc[2][2] = {};
    const int rbase = lane & 15;
    const int ks = lane >> 4;

    for (int k0 = 0; k0 < K; k0 += 64) {
        stage(k0);
        __syncthreads();
        #pragma unroll
        for (int h = 0; h < 2; ++h) {
            bf16x8 af[2], bfr[2];
            #pragma unroll
            for (int mi = 0; mi < 2; ++mi) {
                int r = wr + mi * 16 + rbase;
                int p = (h * 4 + ks) ^ (r & 7);
                af[mi] = *reinterpret_cast<const bf16x8*>(Asl + r * 64 + p * 8);
            }
            #pragma unroll
            for (int ni = 0; ni < 2; ++ni) {
                int r = wc + ni * 16 + rbase;
                int p = (h * 4 + ks) ^ (r & 7);
                bfr[ni] = *reinterpret_cast<const bf16x8*>(Bsl + r * 64 + p * 8);
            }
            #pragma unroll
            for (int mi = 0; mi < 2; ++mi)
                #pragma unroll
                for (int ni = 0; ni < 2; ++ni)
                    acc[mi][ni] = __builtin_amdgcn_mfma_f32_16x16x32_bf16(
                        af[mi], bfr[ni], acc[mi][ni], 0, 0, 0);
        }
        __syncthreads();
    }

    const int colBase = bn + wc + rbase;
    const int rowBase = bm + wr + ks * 4;
    #pragma unroll
    for (int mi = 0; mi < 2; ++mi) {
        #pragma unroll
        for (int j = 0; j < 4; ++j) {
            int r = rowBase + mi * 16 + j;
            if (r >= M) continue;
            long ro = (long)r * Nc;
            #pragma unroll
            for (int ni = 0; ni < 2; ++ni) {
                int cc = colBase + ni * 16;
                if (cc >= Nc) continue;
                float v = acc[mi][ni][j];
                if (bias)  v += bias[cc];
                if (doRelu) v = fmaxf(v, 0.0f);
                if (addC)  v += addC[ro + cc];
                else if (addCb) v += b2f(addCb[ro + cc]);
                if (Cb) Cb[ro + cc] = f2b(v);
                else    C[ro + cc] = v;
            }
        }
    }
}

// ---------------- LayerNorm (wave per row, 4 rows/block) ----------------
static __global__ __launch_bounds__(256)
void ln_k(const float* __restrict__ in, const unsigned short* __restrict__ inb,
          const float* __restrict__ g, const float* __restrict__ b,
          float* __restrict__ out, int Dw, int nrows,
          unsigned short* __restrict__ outb,
          unsigned short* __restrict__ out2b, const int* __restrict__ idx2)
{
    const int row = blockIdx.x * 4 + (threadIdx.x >> 6);
    if (row >= nrows) return;
    const int lane = threadIdx.x & 63;
    const int per = Dw >> 6;
    float v[8];
    float s = 0.f;
    if (inb) {
        const unsigned short* rp = inb + (long)row * Dw;
        for (int i = 0; i < per; ++i) { v[i] = b2f(rp[i * 64 + lane]); s += v[i]; }
    } else {
        const float* rp = in + (long)row * Dw;
        for (int i = 0; i < per; ++i) { v[i] = rp[i * 64 + lane]; s += v[i]; }
    }
    #pragma unroll
    for (int off = 32; off; off >>= 1) s += __shfl_xor(s, off, 64);
    const float mu = s / (float)Dw;
    float var = 0.f;
    for (int i = 0; i < per; ++i) { float d = v[i] - mu; var += d * d; }
    #pragma unroll
    for (int off = 32; off; off >>= 1) var += __shfl_xor(var, off, 64);
    const float rstd = rsqrtf(var / (float)Dw + 1e-5f);
    for (int i = 0; i < per; ++i) {
        int c = i * 64 + lane;
        float o = (v[i] - mu) * rstd * g[c] + b[c];
        if (out)   out[(long)row * Dw + c] = o;
        if (outb)  outb[(long)row * Dw + c] = f2b(o);
        if (out2b) out2b[(long)idx2[row] * Dw + c] = f2b(o);
    }
}

// ---------------- node attention, CSR, 2-way unrolled ----------------
static __global__ __launch_bounds__(256)
void node_attn_csr_k(const unsigned short* __restrict__ qkv,
                     const unsigned short* __restrict__ lgb,
                     const int* __restrict__ goff, const int2* __restrict__ npack,
                     unsigned short* __restrict__ ob)
{
    int node = blockIdx.x * 4 + (threadIdx.x >> 6);
    if (node >= NN) return;
    const int lane = threadIdx.x & 63;
    float qv[8];
    {
        u16x8 q8 = *reinterpret_cast<const u16x8*>(qkv + (long)node * QKVW + lane * 8);
        #pragma unroll
        for (int i = 0; i < 8; ++i) qv[i] = b2f(q8[i]);
    }
    float wva[8] = {0.f, 0.f, 0.f, 0.f, 0.f, 0.f, 0.f, 0.f};
    float zac = 0.f;
    int j = goff[node];
    const int hi = (node + 1 < NN) ? goff[node + 1] : NE;
    const int eoffl = (lane & 7) * 8;

    for (; j + 2 <= hi; j += 2) {
        int2 pa = npack[j], pb = npack[j + 1];
        u16x8 kA = *reinterpret_cast<const u16x8*>(qkv + (long)pa.y * QKVW + 512 + lane * 8);
        u16x8 vA = *reinterpret_cast<const u16x8*>(qkv + (long)pa.y * QKVW + 1024 + lane * 8);
        u16x8 eA = *reinterpret_cast<const u16x8*>(lgb + (long)pa.x * ED + eoffl);
        u16x8 kB = *reinterpret_cast<const u16x8*>(qkv + (long)pb.y * QKVW + 512 + lane * 8);
        u16x8 vB = *reinterpret_cast<const u16x8*>(qkv + (long)pb.y * QKVW + 1024 + lane * 8);
        u16x8 eB = *reinterpret_cast<const u16x8*>(lgb + (long)pb.x * ED + eoffl);
        float edA[8], vvA[8], edB[8], vvB[8];
        float pA = 0.f, pB = 0.f;
        #pragma unroll
        for (int i = 0; i < 8; ++i) {
            edA[i] = b2f(eA[i]); vvA[i] = b2f(vA[i]);
            pA = fmaf(b2f(kA[i]) + edA[i], qv[i], pA);
            edB[i] = b2f(eB[i]); vvB[i] = b2f(vB[i]);
            pB = fmaf(b2f(kB[i]) + edB[i], qv[i], pB);
        }
        pA += __shfl_xor(pA, 1, 64); pA += __shfl_xor(pA, 2, 64); pA += __shfl_xor(pA, 4, 64);
        pB += __shfl_xor(pB, 1, 64); pB += __shfl_xor(pB, 2, 64); pB += __shfl_xor(pB, 4, 64);
        float wA = expf(fminf(fmaxf(pA * 0.125f, -10.0f), 10.0f));
        float wB = expf(fminf(fmaxf(pB * 0.125f, -10.0f), 10.0f));
        #pragma unroll
        for (int i = 0; i < 8; ++i) {
            wva[i] = fmaf(wA, vvA[i] + edA[i], wva[i]);
            wva[i] = fmaf(wB, vvB[i] + edB[i], wva[i]);
        }
        zac += wA + wB;
    }
    for (; j < hi; ++j) {
        int2 pa = npack[j];
        u16x8 kA = *reinterpret_cast<const u16x8*>(qkv + (long)pa.y * QKVW + 512 + lane * 8);
        u16x8 vA = *reinterpret_cast<const u16x8*>(qkv + (long)pa.y * QKVW + 1024 + lane * 8);
        u16x8 eA = *reinterpret_cast<const u16x8*>(lgb + (long)pa.x * ED + eoffl);
        float edA[8], vvA[8];
        float pA = 0.f;
        #pragma unroll
        for (int i = 0; i < 8; ++i) {
            edA[i] = b2f(eA[i]); vvA[i] = b2f(vA[i]);
            pA = fmaf(b2f(kA[i]) + edA[i], qv[i], pA);
        }
        pA += __shfl_xor(pA, 1, 64); pA += __shfl_xor(pA, 2, 64); pA += __shfl_xor(pA, 4, 64);
        float wA = expf(fminf(fmaxf(pA * 0.125f, -10.0f), 10.0f));
        #pragma unroll
        for (int i = 0; i < 8; ++i) wva[i] = fmaf(wA, vvA[i] + edA[i], wva[i]);
        zac += wA;
    }
    const float inv = 1.0f / fmaxf(zac, 1e-9f);
    u16x8 o8;
    #pragma unroll
    for (int i = 0; i < 8; ++i) o8[i] = f2b(wva[i] * inv);
    *reinterpret_cast<u16x8*>(ob + (long)node * DD + lane * 8) = o8;
}

// ---------------- line-graph attention, CSR, (edge,head)-per-lane ----------
static __global__ __launch_bounds__(256)
void lg_attn_csr_k(const unsigned short* __restrict__ qeb,
                   const unsigned short* __restrict__ keve,
                   const int* __restrict__ eoff, const int* __restrict__ esrc,
                   unsigned short* __restrict__ oeb)
{
    int d = blockIdx.x * 4 + (threadIdx.x >> 6);
    if (d >= NEL) return;
    const int lane = threadIdx.x & 63;
    const int he = lane & 7;
    const int ee = lane >> 3;
    const int hd = lane >> 3;
    float qv8[8];
    {
        u16x8 q8 = *reinterpret_cast<const u16x8*>(qeb + (long)d * ED + he * 8);
        #pragma unroll
        for (int i = 0; i < 8; ++i) qv8[i] = b2f(q8[i]);
    }
    const float qvd = b2f(qeb[(long)d * ED + lane]);
    float oa = 0.f, zac = 0.f;
    int j = eoff[d];
    const int hi = (d + 1 < NEL) ? eoff[d + 1] : NLG;

    for (; j + 8 <= hi; j += 8) {
        int sMine = esrc[j + ee];
        u16x8 k8 = *reinterpret_cast<const u16x8*>(keve + (long)sMine * 128 + he * 8);
        float p = 0.f;
        #pragma unroll
        for (int i = 0; i < 8; ++i) p = fmaf(b2f(k8[i]), qv8[i], p);
        float w = expf(fminf(fmaxf(p * 0.35355339059327373f, -10.0f), 10.0f));
        #pragma unroll
        for (int u = 0; u < 8; ++u) {
            float wu = __shfl(w, u * 8 + hd, 64);
            int   su = esrc[j + u];
            float vv = b2f(keve[(long)su * 128 + 64 + lane]);
            oa = fmaf(wu, vv, oa);
            zac += wu;
        }
    }
    for (; j < hi; ++j) {
        int s = esrc[j];
        float kv = b2f(keve[(long)s * 128 + lane]);
        float vv = b2f(keve[(long)s * 128 + 64 + lane]);
        float p = kv * qvd;
        p += __shfl_xor(p, 1, 64); p += __shfl_xor(p, 2, 64); p += __shfl_xor(p, 4, 64);
        float w = expf(fminf(fmaxf(p * 0.35355339059327373f, -10.0f), 10.0f));
        oa = fmaf(w, vv, oa);
        zac += w;
    }
    oeb[(long)d * ED + lane] = f2b(oa / fmaxf(zac, 1e-9f));
}

// ---------------- host ----------------
static inline void run_gemm(hipStream_t st, const unsigned short* A,
                            const unsigned short* Bt, const float* bias,
                            const float* addC, const unsigned short* addCb,
                            float* C, unsigned short* Cb,
                            int M, int K, int Nc, int relu)
{
    dim3 g((Nc + 63) / 64, (M + 63) / 64);
    gemm_bf16_k<<<g, 256, 0, st>>>(A, nullptr, nullptr, Bt, bias, addC, addCb,
                                   C, Cb, M, K, Nc, relu, 0);
}

extern "C" void kernel_launch(void* const* d_in, const int* in_sizes, int n_in,
                              void* d_out, int out_size, void* d_ws, size_t ws_size,
                              hipStream_t stream)
{
    const float* x_in  = (const float*)d_in[0];
    const float* rel   = (const float*)d_in[1];
    const float* Wq    = (const float*)d_in[2];
    const float* bq    = (const float*)d_in[3];
    const float* Wk    = (const float*)d_in[4];
    const float* Wv    = (const float*)d_in[5];
    const float* Wo    = (const float*)d_in[6];
    const float* bo    = (const float*)d_in[7];
    const float* ln1g  = (const float*)d_in[8];
    const float* ln1b  = (const float*)d_in[9];
    const float* F1    = (const float*)d_in[10];
    const float* f1b   = (const float*)d_in[11];
    const float* F2    = (const float*)d_in[12];
    const float* f2b_  = (const float*)d_in[13];
    const float* ln2g  = (const float*)d_in[14];
    const float* ln2b  = (const float*)d_in[15];
    const float* Eq    = (const float*)d_in[16];
    const float* eqb   = (const float*)d_in[17];
    const float* Ek    = (const float*)d_in[18];
    const float* Ev    = (const float*)d_in[19];
    const float* Eo    = (const float*)d_in[20];
    const float* eob   = (const float*)d_in[21];
    const float* Ns    = (const float*)d_in[22];
    const float* nsb   = (const float*)d_in[23];
    const float* Nd    = (const float*)d_in[24];
    const float* ndb   = (const float*)d_in[25];
    const float* eln1g = (const float*)d_in[26];
    const float* eln1b = (const float*)d_in[27];
    const float* G1    = (const float*)d_in[28];
    const float* g1b   = (const float*)d_in[29];
    const float* G2    = (const float*)d_in[30];
    const float* g2b   = (const float*)d_in[31];
    const float* eln2g = (const float*)d_in[32];
    const float* eln2b = (const float*)d_in[33];
    const int* edge_feat   = (const int*)d_in[34];
    const int* local_index = (const int*)d_in[35];
    const int* src_ids     = (const int*)d_in[36];
    const int* dst_ids     = (const int*)d_in[37];
    const int* g_src       = (const int*)d_in[38];
    const int* g_dst       = (const int*)d_in[39];
    const int* lg_src      = (const int*)d_in[40];
    const int* lg_dst      = (const int*)d_in[41];

    // outputs live in d_out
    float* xbuf = (float*)d_out;                   // (NN, DD)
    float* el   = xbuf + (size_t)NN * DD;          // (NEL, ED)

    // ---- workspace layout ----
    float* W = (float*)d_ws;
    size_t off = 0;
    auto alloc = [&](size_t n) { float* p = W + off; off += (n + 63) & ~(size_t)63; return p; };
    float* qkvb = alloc((size_t)NL * QKVW);
    float* kvb  = alloc((size_t)NL * 128);
    float* qb2  = alloc((size_t)NL * ED);

    unsigned short* bp = (unsigned short*)(W + off);
    size_t boff = 0;
    auto balloc = [&](size_t n) { unsigned short* p = bp + boff; boff += (n + 63) & ~(size_t)63; return p; };
    unsigned short* lgb = balloc((size_t)NE * ED);
    unsigned short* xb  = balloc((size_t)NN * DD);
    unsigned short* qkv = balloc((size_t)NN * QKVW);
    unsigned short* keve = balloc((size_t)NEL * 128);   // OWN buffer (no qkv alias!)
    unsigned short* elb = balloc((size_t)NEL * ED);
    unsigned short* e1b = balloc((size_t)NEL * ED);
    unsigned short* heb = balloc((size_t)NEL * ED);
    unsigned short* qeb = balloc((size_t)NEL * ED);
    unsigned short* fgb = balloc((size_t)NN * 4 * DD);
    unsigned short* t0b = balloc((size_t)NN * DD);    // pre-LN h
    unsigned short* t2b = balloc((size_t)NEL * ED);   // pre-LN he
    unsigned short* t3b = balloc((size_t)NEL * ED);   // pre-LN edge out
    unsigned short* xpb = balloc((size_t)NN * DD);    // pre-LN x
    unsigned short* hb   = qkv;                       // safe: dead before next QKV write
    unsigned short* ob   = fgb;                       // safe: consumed before G1 writes fgb
    unsigned short* WqkvT = balloc((size_t)NL * QKVW * DD);
    unsigned short* WoT  = balloc((size_t)NL * DD * DD);
    unsigned short* F1T  = balloc((size_t)NL * DD * 4 * DD);
    unsigned short* F2T  = balloc((size_t)NL * 4 * DD * DD);
    unsigned short* KVET = balloc((size_t)NL * 128 * 576);
    unsigned short* QET  = balloc((size_t)NL * 64 * 576);
    unsigned short* EoT  = balloc((size_t)NL * ED * ED);
    unsigned short* G1T  = balloc((size_t)NL * ED * 4 * ED);
    unsigned short* G2T  = balloc((size_t)NL * 4 * ED * ED);
    int* ip = (int*)(bp + ((boff + 63) & ~(size_t)63));
    size_t ioff = 0;
    auto ialloc = [&](size_t n) { int* p = ip + ioff; ioff += (n + 63) & ~(size_t)63; return p; };
    int* gcnt = ialloc(NN);
    int* goff = ialloc(NN);
    int* gcur = ialloc(NN);
    int2* npack = (int2*)ialloc(2 * (size_t)NE);
    int* ecnt = ialloc(NEL);
    int* eoff = ialloc(NEL);
    int* ecur = ialloc(NEL);
    int* esrc = ialloc(NLG);
    int* bsum = ialloc(1024);

    // ---- fused weight prep: one kernel, 15 segments ----
    TT tt;
    int bc = 0, si = 0;
    auto seg = [&](const float* src, unsigned short* dst, int K, int N,
                   long lstride, int rowStride, int rowOff, int colOff) {
        tt.src[si] = src; tt.dst[si] = dst; tt.lstride[si] = lstride;
        tt.K[si] = K; tt.Nn[si] = N; tt.rowStride[si] = rowStride;
        tt.rowOff[si] = rowOff; tt.colOff[si] = colOff;
        tt.blkStart[si] = bc;
        bc += (K / 32) * (N / 32) * NL;
        ++si;
    };
    seg(Wq, WqkvT, 512, 512, (long)QKVW * DD, DD, 0, 0);
    seg(Wk, WqkvT, 512, 512, (long)QKVW * DD, DD, 512, 0);
    seg(Wv, WqkvT, 512, 512, (long)QKVW * DD, DD, 1024, 0);
    seg(Wo, WoT, 512, 512, (long)DD * DD, DD, 0, 0);
    seg(F1, F1T, 512, 2048, (long)DD * 4 * DD, DD, 0, 0);
    seg(F2, F2T, 2048, 512, (long)4 * DD * DD, 4 * DD, 0, 0);
    seg(Ek, KVET, 64, 64, (long)128 * 576, 576, 0, 0);
    seg(Nd, KVET, 512, 64, (long)128 * 576, 576, 0, 64);
    seg(Ev, KVET, 64, 64, (long)128 * 576, 576, 64, 0);
    seg(Nd, KVET, 512, 64, (long)128 * 576, 576, 64, 64);
    seg(Eq, QET, 64, 64, (long)64 * 576, 576, 0, 0);
    seg(Ns, QET, 512, 64, (long)64 * 576, 576, 0, 64);
    seg(Eo, EoT, 64, 64, (long)ED * ED, ED, 0, 0);
    seg(G1, G1T, 64, 256, (long)ED * 4 * ED, ED, 0, 0);
    seg(G2, G2T, 256, 64, (long)4 * ED * ED, 4 * ED, 0, 0);
    ttrans_all_k<<<bc, 256, 0, stream>>>(tt);
    biases_k<<<(NL * QKVW + 255) / 256, 256, 0, stream>>>(bq, ndb, eqb, nsb, qkvb, kvb, qb2);

    // ---- CSR build (both graphs per stage; scatter+pack fused) ----
    const int nbG = (NN + 255) / 256, nbE = (NEL + 255) / 256;
    zero2_k<<<nbE, 256, 0, stream>>>(gcnt, ecnt);
    hist2_k<<<(NE + NLG + 255) / 256, 256, 0, stream>>>(g_dst, lg_dst, gcnt, ecnt);
    scanA2_k<<<nbG + nbE, 256, 0, stream>>>(gcnt, ecnt, goff, eoff, bsum, nbG);
    scanB2_k<<<2, 1024, 0, stream>>>(bsum, nbG, nbE);
    scanC2_k<<<nbG + nbE, 256, 0, stream>>>(bsum, goff, eoff, gcur, ecur, nbG);
    scatterpack_k<<<(NE + NLG + 255) / 256, 256, 0, stream>>>(
        g_dst, lg_dst, g_src, lg_src, gcur, ecur, npack, esrc);

    // ---- fused init (castcopy + lgb + el gather) ----
    {
        long tot = (long)NN * DD + (long)NE * ED + (long)NEL * ED;
        init_all_k<<<(int)((tot + 255) / 256), 256, 0, stream>>>(
            x_in, rel, edge_feat, local_index, xbuf, xb, lgb, el, elb);
    }

    const int rQ = (NN + 63) / 64;    // 157
    const int rE = (NEL + 63) / 64;   // 938

    for (int i = 0; i < NL; ++i) {
        size_t oD2 = (size_t)i * DD * DD, oE2 = (size_t)i * ED * ED;

        // ---- merged {QKV | KVE | QE}: all read xb + elb; disjoint outputs ----
        {
            GSegs G;
            G.s[0] = { xb, nullptr, nullptr, WqkvT + (size_t)i * QKVW * DD,
                       qkvb + (size_t)i * QKVW, nullptr, qkv,
                       NN, DD, QKVW, 0, 0, QKVW / 64 };
            int b0 = (QKVW / 64) * rQ;                         // 3768
            G.s[1] = { elb, xb, dst_ids, KVET + (size_t)i * 128 * 576,
                       kvb + (size_t)i * 128, nullptr, keve,
                       NEL, 576, 128, 64, b0, 2 };
            int b1 = b0 + 2 * rE;                              // 5644
            G.s[2] = { elb, xb, src_ids, QET + (size_t)i * 64 * 576,
                       qb2 + (size_t)i * 64, nullptr, qeb,
                       NEL, 576, 64, 64, b1, 1 };
            G.nseg = 3; G.total = b1 + rE;                     // 6582
            gemmseg_k<<<G.total, 256, 0, stream>>>(G);
        }

        // ---- both attentions (independent) ----
        node_attn_csr_k<<<NN / 4, 256, 0, stream>>>(qkv, lgb, goff, npack, ob);
        lg_attn_csr_k<<<NEL / 4, 256, 0, stream>>>(qeb, keve, eoff, esrc, e1b);

        // ---- merged {Wo | Eo} ----
        {
            GSegs G;
            G.s[0] = { ob, nullptr, nullptr, WoT + oD2,
                       bo + (size_t)i * DD, xb, t0b,
                       NN, DD, DD, 0, 0, DD / 64 };
            int b0 = (DD / 64) * rQ;                           // 1256
            G.s[1] = { e1b, nullptr, nullptr, EoT + oE2,
                       eob + (size_t)i * ED, elb, t2b,
                       NEL, ED, ED, 0, b0, 1 };
            G.s[2] = G.s[1];
            G.nseg = 2; G.total = b0 + rE;                     // 2194
            gemmseg_k<<<G.total, 256, 0, stream>>>(G);
        }

        ln_k<<<(NN + 3) / 4, 256, 0, stream>>>(nullptr, t0b, ln1g + (size_t)i * DD, ln1b + (size_t)i * DD,
                                               nullptr, DD, NN, hb, nullptr, nullptr);
        ln_k<<<(NEL + 3) / 4, 256, 0, stream>>>(nullptr, t2b, eln1g + (size_t)i * ED, eln1b + (size_t)i * ED,
                                                nullptr, ED, NEL, heb, nullptr, nullptr);

        // ---- edge FFN ----
        run_gemm(stream, heb, G1T + (size_t)i * ED * 4 * ED, g1b + (size_t)i * 4 * ED,
                 nullptr, nullptr, nullptr, fgb, NEL, ED, 4 * ED, 1);
        run_gemm(stream, fgb, G2T + (size_t)i * 4 * ED * ED, g2b + (size_t)i * ED,
                 nullptr, heb, nullptr, t3b, NEL, 4 * ED, ED, 0);
        ln_k<<<(NEL + 3) / 4, 256, 0, stream>>>(nullptr, t3b, eln2g + (size_t)i * ED, eln2b + (size_t)i * ED,
                                                el, ED, NEL, elb, lgb, local_index);

        // ---- node FFN ----
        run_gemm(stream, hb, F1T + (size_t)i * DD * 4 * DD, f1b + (size_t)i * 4 * DD,
                 nullptr, nullptr, nullptr, fgb, NN, DD, 4 * DD, 1);
        run_gemm(stream, fgb, F2T + (size_t)i * 4 * DD * DD, f2b_ + (size_t)i * DD,
                 nullptr, hb, nullptr, xpb, NN, 2048, DD, 0);
        ln_k<<<(NN + 3) / 4, 256, 0, stream>>>(nullptr, xpb, ln2g + (size_t)i * DD, ln2b + (size_t)i * DD,
                                               xbuf, DD, NN, xb, nullptr, nullptr);
    }
    // outputs already in d_out
}